// Round 8
// baseline (358.933 us; speedup 1.0000x reference)
//
#include <hip/hip_runtime.h>
#include <hip/hip_cooperative_groups.h>
#include <math.h>

namespace cg = cooperative_groups;

#define N_NODES 100000
#define N_EDGES 3200000
#define NPB    256                               // nodes per bucket
#define NBUCK  ((N_NODES + NPB - 1) / NPB)       // 391
#define NBLKA  256                               // pass-A blocks (region granularity!)
#define BBA    1024                              // pass-A block size (occupancy)
#define EPB    ((N_EDGES + NBLKA - 1) / NBLKA)   // 12500
#define NB_BLK ((N_NODES + 255) / 256)

// ws words: dinv N + rowstart N + rowend N + adj E + S max(32N,E)
//           + bt (NBUCK+1) + bt2 (NBUCK+1) + flag.
//           cmat (NBUCK*NBLKA = 100096) ALIASES adj (dead before adj written).
#define NEW_WS_WORDS (3u*N_NODES + N_EDGES + 3200000u + 2u*(NBUCK + 1u) + 2u)
#define NEW_WS_BYTES (NEW_WS_WORDS * 4u)
// atomic fallback path (R4): 33N floats + flag
#define ATOMIC_WS_BYTES ((33u*N_NODES + 16u) * 4u)

// ---------------------------------------------------------------------------
// dtype probe: edge_index may be int32 or raw int64 (reference uses int64).
__global__ void k_detect_i64(const int* __restrict__ ei_words, int* __restrict__ flag) {
    if (blockIdx.x == 0 && threadIdx.x == 0) {
        int allzero = 1;
        for (int i = 0; i < 64; i++)
            if (ei_words[2 * i + 1] != 0) allzero = 0;
        *flag = allzero;  // 1 => int64 layout
    }
}

__device__ __forceinline__ unsigned load_idx(const int* p32, const long long* p64,
                                             int is64, int e) {
    return is64 ? (unsigned)(unsigned long long)p64[e] : (unsigned)p32[e];
}

// ---------------------------------------------------------------------------
// COOPERATIVE build pass-A: detect + count + scan + scatter in ONE kernel.
// 256 blocks x 1024 threads (1 block/CU, co-resident by coop-launch contract).
__global__ __launch_bounds__(1024) void k_build_graph(
    const int* __restrict__ src32, const long long* __restrict__ src64,
    const int* __restrict__ dst32, const long long* __restrict__ dst64,
    int* __restrict__ cmat, int* __restrict__ bt, int* __restrict__ bt2,
    int* __restrict__ P) {
    cg::grid_group grid = cg::this_grid();
    __shared__ int lc[NBUCK];        // counts, later scatter cursors
    __shared__ int sb[512];          // scan scratch
    __shared__ int pref[NBUCK + 1];  // bucket prefix
    __shared__ int s_is64;
    int t = threadIdx.x, blk = blockIdx.x;

    // p0: zero bt (block 0), dtype detect (per block), zero local counts
    if (blk == 0)
        for (int i = t; i < NBUCK; i += 1024) bt[i] = 0;
    if (t == 0) {
        int az = 1;
        for (int i = 0; i < 64; i++)
            if (src32[2 * i + 1] != 0) az = 0;
        s_is64 = az;
    }
    for (int i = t; i < NBUCK; i += 1024) lc[i] = 0;
    __syncthreads();
    int is64 = s_is64;
    grid.sync();  // bt zeroed everywhere

    // p1: per-block bucket counts; publish cmat row + global bucket totals
    int e0 = blk * EPB;
    int e1 = e0 + EPB; if (e1 > N_EDGES) e1 = N_EDGES;
    for (int e = e0 + t; e < e1; e += 1024) {
        unsigned d = load_idx(dst32, dst64, is64, e);
        if (d < N_NODES) atomicAdd(&lc[d >> 8], 1);
    }
    __syncthreads();
    for (int i = t; i < NBUCK; i += 1024) {
        cmat[blk * NBUCK + i] = lc[i];
        atomicAdd(&bt[i], lc[i]);
    }
    grid.sync();  // all cmat rows + bt totals complete

    // p2: every block computes the full bucket prefix; then column scans
    if (t < 512) sb[t] = (t < NBUCK) ? bt[t] : 0;
    __syncthreads();
    for (int off = 1; off < 512; off <<= 1) {
        int v = (t < 512 && t >= off) ? sb[t - off] : 0;
        __syncthreads();
        if (t < 512) sb[t] += v;
        __syncthreads();
    }
    if (t < NBUCK) pref[t] = (t == 0) ? 0 : sb[t - 1];
    if (t == 0) pref[NBUCK] = sb[NBUCK - 1];
    __syncthreads();
    if (blk == 0)  // publish prefix for k_bbuild (bt2 is fresh memory: no race)
        for (int i = t; i < NBUCK + 1; i += 1024) bt2[i] = pref[i];
    // column scans: bucket blk handled by threads 0..255, bucket blk+256 by 256..511
    {
        int half = t >> 8;   // 0..3
        int lane = t & 255;
        int b = (half == 0) ? blk : (half == 1 ? blk + 256 : 0x7fffffff);
        int valid = (half < 2) && (b < NBUCK);
        if (valid) sb[half * 256 + lane] = cmat[lane * NBUCK + b];
        __syncthreads();
        for (int off = 1; off < 256; off <<= 1) {
            int v = (valid && lane >= off) ? sb[half * 256 + lane - off] : 0;
            __syncthreads();
            if (valid && lane >= off) sb[half * 256 + lane] += v;
            __syncthreads();
        }
        if (valid)
            cmat[lane * NBUCK + b] =
                ((lane == 0) ? 0 : sb[half * 256 + lane - 1]) + pref[b];
    }
    grid.sync();  // cmat now holds absolute scatter offsets

    // p3: scatter packed entries (dstLow<<17 | src) into bucket-major P
    for (int i = t; i < NBUCK; i += 1024) lc[i] = cmat[blk * NBUCK + i];
    __syncthreads();
    for (int e = e0 + t; e < e1; e += 1024) {
        unsigned d = load_idx(dst32, dst64, is64, e);
        if (d < N_NODES) {
            unsigned s = load_idx(src32, src64, is64, e);
            int pos = atomicAdd(&lc[d >> 8], 1);
            P[pos] = (int)(((d & 255u) << 17) | (s & 0x1FFFFu));
        }
    }
}

// ---------------------------------------------------------------------------
// Fallback pass-A kernels (used if cooperative launch is unavailable)
__global__ __launch_bounds__(BBA) void k_bcount(const int* __restrict__ dst32,
                                                const long long* __restrict__ dst64,
                                                const int* __restrict__ flag,
                                                int* __restrict__ cmat) {
    __shared__ int lc[NBUCK];
    int t = threadIdx.x, blk = blockIdx.x;
    for (int i = t; i < NBUCK; i += BBA) lc[i] = 0;
    __syncthreads();
    int is64 = *flag;
    int e0 = blk * EPB;
    int e1 = e0 + EPB; if (e1 > N_EDGES) e1 = N_EDGES;
    for (int e = e0 + t; e < e1; e += BBA) {
        unsigned d = load_idx(dst32, dst64, is64, e);
        if (d < N_NODES) atomicAdd(&lc[d >> 8], 1);
    }
    __syncthreads();
    for (int b = t; b < NBUCK; b += BBA) cmat[blk * NBUCK + b] = lc[b];
}

__global__ __launch_bounds__(256) void k_bsum(const int* __restrict__ cmat,
                                              int* __restrict__ bt) {
    int b = blockIdx.x, t = threadIdx.x;
    int v = cmat[t * NBUCK + b];
#pragma unroll
    for (int off = 32; off > 0; off >>= 1) v += __shfl_down(v, off, 64);
    __shared__ int s[4];
    if ((t & 63) == 0) s[t >> 6] = v;
    __syncthreads();
    if (t == 0) bt[b] = s[0] + s[1] + s[2] + s[3];
}

__global__ __launch_bounds__(512) void k_btscan(int* __restrict__ bt) {
    __shared__ int s[512];
    int t = threadIdx.x;
    s[t] = (t < NBUCK) ? bt[t] : 0;
    __syncthreads();
    for (int off = 1; off < 512; off <<= 1) {
        int v = (t >= off) ? s[t - off] : 0;
        __syncthreads();
        s[t] += v;
        __syncthreads();
    }
    if (t < NBUCK) bt[t] = (t == 0) ? 0 : s[t - 1];
    if (t == 0) bt[NBUCK] = s[NBUCK - 1];
}

__global__ __launch_bounds__(256) void k_boffs(int* __restrict__ cmat,
                                               const int* __restrict__ bt) {
    __shared__ int s[256];
    int b = blockIdx.x, t = threadIdx.x;
    s[t] = cmat[t * NBUCK + b];
    __syncthreads();
    for (int off = 1; off < 256; off <<= 1) {
        int v = (t >= off) ? s[t - off] : 0;
        __syncthreads();
        s[t] += v;
        __syncthreads();
    }
    cmat[t * NBUCK + b] = ((t == 0) ? 0 : s[t - 1]) + bt[b];
}

__global__ __launch_bounds__(BBA) void k_bscatter(const int* __restrict__ src32,
                                                  const long long* __restrict__ src64,
                                                  const int* __restrict__ dst32,
                                                  const long long* __restrict__ dst64,
                                                  const int* __restrict__ flag,
                                                  const int* __restrict__ cmat,
                                                  int* __restrict__ P) {
    __shared__ int cur[NBUCK];
    int t = threadIdx.x, blk = blockIdx.x;
    for (int i = t; i < NBUCK; i += BBA) cur[i] = cmat[blk * NBUCK + i];
    __syncthreads();
    int is64 = *flag;
    int e0 = blk * EPB;
    int e1 = e0 + EPB; if (e1 > N_EDGES) e1 = N_EDGES;
    for (int e = e0 + t; e < e1; e += BBA) {
        unsigned d = load_idx(dst32, dst64, is64, e);
        if (d < N_NODES) {
            unsigned s = load_idx(src32, src64, is64, e);
            int pos = atomicAdd(&cur[d >> 8], 1);
            P[pos] = (int)(((d & 255u) << 17) | (s & 0x1FFFFu));
        }
    }
}

// Pass B: per-bucket CSR build (one 512-thread block per 256-node bucket).
__global__ __launch_bounds__(512) void k_bbuild(const int* __restrict__ P,
                                                const int* __restrict__ bt,
                                                int* __restrict__ adj,
                                                int* __restrict__ rowstart,
                                                int* __restrict__ rowend,
                                                float* __restrict__ dinv) {
    __shared__ int cnt[NPB];
    __shared__ int s[NPB];
    int b = blockIdx.x, t = threadIdx.x;
    int bo = bt[b], be = bt[b + 1];
    if (t < NPB) cnt[t] = 0;
    __syncthreads();
    for (int i = bo + t; i < be; i += 512) atomicAdd(&cnt[P[i] >> 17], 1);
    __syncthreads();
    if (t < NPB) s[t] = cnt[t];
    __syncthreads();
    for (int off = 1; off < NPB; off <<= 1) {
        int v = (t >= off && t < NPB) ? s[t - off] : 0;
        __syncthreads();
        if (t < NPB) s[t] += v;
        __syncthreads();
    }
    int ex = (t == 0 || t >= NPB) ? 0 : s[t - 1];
    int node = b * NPB + t;
    if (t < NPB && node < N_NODES) {
        rowstart[node] = bo + ex;
        rowend[node]   = bo + ex + cnt[t];
        dinv[node]     = rsqrtf((float)cnt[t] + 1.0f);
    }
    __syncthreads();
    if (t < NPB) s[t] = ex;  // cursors
    __syncthreads();
    for (int i = bo + t; i < be; i += 512) {
        int ent = P[i];
        int pos = bo + atomicAdd(&s[ent >> 17], 1);
        adj[pos] = ent & 0x1FFFF;
    }
}

// ---------------------------------------------------------------------------
// Layer-1 GEMM (R6-proven anchor): 16 nodes/block, lane = (node, f).
__global__ __launch_bounds__(256) void k_gemm1(const float* __restrict__ h,
                                               const float* __restrict__ W,
                                               const float* __restrict__ dinv,
                                               float* __restrict__ xs,
                                               float* acc) {
    __shared__ float Wt[16 * 132];
    __shared__ float Hs[16 * 132];
    int tid = threadIdx.x;
    for (int i = tid; i < 2048; i += 256) {
        int k = i >> 4, f = i & 15;
        Wt[f * 132 + k] = W[i];
    }
    int nodeBase = blockIdx.x * 16;
    for (int i = tid; i < 512; i += 256) {
        int r = i >> 5, c = i & 31;
        float4 v = ((const float4*)(h + (size_t)(nodeBase + r) * 128))[c];
        *((float4*)&Hs[r * 132 + c * 4]) = v;
    }
    __syncthreads();
    int nl = tid >> 4;
    int f  = tid & 15;
    int n  = nodeBase + nl;
    const float* hr = &Hs[nl * 132];
    const float* wr = &Wt[f * 132];
    float s = 0.0f;
#pragma unroll
    for (int k = 0; k < 128; k++) s += hr[k] * wr[k];
    s *= dinv[n];
    xs[n * 16 + f]  = s;
    acc[n * 16 + f] = s;
}

template <int FI, int FO>
__global__ __launch_bounds__(256) void k_gemm_small(const float* __restrict__ x,
                                                    const float* __restrict__ W,
                                                    const float* __restrict__ dinv,
                                                    float* __restrict__ xs,
                                                    float* acc) {
    int i = blockIdx.x * 256 + threadIdx.x;
    if (i >= N_NODES * FO) return;
    int n = i / FO, f = i % FO;
    float s = 0.0f;
#pragma unroll
    for (int k = 0; k < FI; k++) s += x[n * FI + k] * W[k * FO + f];
    s *= dinv[n];
    xs[i] = s;
    acc[i] = s;
}

// ---------------------------------------------------------------------------
// Pull F=16 fused with layer-2 GEMM.
__global__ __launch_bounds__(256) void k_pull16g2(const float* __restrict__ xs,
                                                  const int* __restrict__ adj,
                                                  const int* __restrict__ rowstart,
                                                  const int* __restrict__ rowend,
                                                  const float* __restrict__ dinv,
                                                  const float* __restrict__ b,
                                                  const float* __restrict__ W2,
                                                  float* __restrict__ xs2) {
    const float4* xs4 = (const float4*)xs;
    int t = threadIdx.x;
    int g = t >> 4;          // node within block (16 nodes/block)
    int q = t & 15;
    int fv = q & 3;          // which float4 of the 16-float row
    int k  = q >> 2;         // edge slot 0..3
    int n = blockIdx.x * 16 + g;
    if (n >= N_NODES) return;
    int s0 = rowstart[n], e0 = rowend[n];
    float4 a0 = make_float4(0.f, 0.f, 0.f, 0.f);
    float4 a1 = a0, a2 = a0, a3 = a0;
    int j = s0 + k;
    for (; j + 12 < e0; j += 16) {
        int i0 = adj[j], i1 = adj[j + 4], i2 = adj[j + 8], i3 = adj[j + 12];
        float4 v0 = xs4[i0 * 4 + fv];
        float4 v1 = xs4[i1 * 4 + fv];
        float4 v2 = xs4[i2 * 4 + fv];
        float4 v3 = xs4[i3 * 4 + fv];
        a0.x += v0.x; a0.y += v0.y; a0.z += v0.z; a0.w += v0.w;
        a1.x += v1.x; a1.y += v1.y; a1.z += v1.z; a1.w += v1.w;
        a2.x += v2.x; a2.y += v2.y; a2.z += v2.z; a2.w += v2.w;
        a3.x += v3.x; a3.y += v3.y; a3.z += v3.z; a3.w += v3.w;
    }
    for (; j < e0; j += 4) {
        float4 v = xs4[adj[j] * 4 + fv];
        a0.x += v.x; a0.y += v.y; a0.z += v.z; a0.w += v.w;
    }
    float4 acc;
    acc.x = (a0.x + a1.x) + (a2.x + a3.x);
    acc.y = (a0.y + a1.y) + (a2.y + a3.y);
    acc.z = (a0.z + a1.z) + (a2.z + a3.z);
    acc.w = (a0.w + a1.w) + (a2.w + a3.w);
#pragma unroll
    for (int off = 4; off <= 8; off <<= 1) {
        acc.x += __shfl_xor(acc.x, off, 64);
        acc.y += __shfl_xor(acc.y, off, 64);
        acc.z += __shfl_xor(acc.z, off, 64);
        acc.w += __shfl_xor(acc.w, off, 64);
    }
    if (k == 0) {
        float4 self = xs4[n * 4 + fv];
        float di = dinv[n];
        float4 bb = ((const float4*)b)[fv];
        float4 o;
        o.x = tanhf(di * (acc.x + self.x) + bb.x);
        o.y = tanhf(di * (acc.y + self.y) + bb.y);
        o.z = tanhf(di * (acc.z + self.z) + bb.z);
        o.w = tanhf(di * (acc.w + self.w) + bb.w);
        const float4* W2r = (const float4*)W2;
        float4 w0 = W2r[4 * fv + 0], w1 = W2r[4 * fv + 1];
        float4 w2 = W2r[4 * fv + 2], w3 = W2r[4 * fv + 3];
        float4 p;
        p.x = o.x * w0.x + o.y * w1.x + o.z * w2.x + o.w * w3.x;
        p.y = o.x * w0.y + o.y * w1.y + o.z * w2.y + o.w * w3.y;
        p.z = o.x * w0.z + o.y * w1.z + o.z * w2.z + o.w * w3.z;
        p.w = o.x * w0.w + o.y * w1.w + o.z * w2.w + o.w * w3.w;
        p.x += __shfl_xor(p.x, 1, 64); p.x += __shfl_xor(p.x, 2, 64);
        p.y += __shfl_xor(p.y, 1, 64); p.y += __shfl_xor(p.y, 2, 64);
        p.z += __shfl_xor(p.z, 1, 64); p.z += __shfl_xor(p.z, 2, 64);
        p.w += __shfl_xor(p.w, 1, 64); p.w += __shfl_xor(p.w, 2, 64);
        float pv = (fv == 0) ? p.x : (fv == 1) ? p.y : (fv == 2) ? p.z : p.w;
        xs2[n * 4 + fv] = pv * di;
    }
}

// Pull F=4 fused with layer-3 GEMM.
__global__ __launch_bounds__(256) void k_pull4g3(const float* __restrict__ xs,
                                                 const int* __restrict__ adj,
                                                 const int* __restrict__ rowstart,
                                                 const int* __restrict__ rowend,
                                                 const float* __restrict__ dinv,
                                                 const float* __restrict__ b,
                                                 const float* __restrict__ W3,
                                                 float* __restrict__ xs3) {
    const float4* xs4 = (const float4*)xs;
    int t = threadIdx.x;
    int g = t >> 3;          // node within block (32 nodes/block)
    int q = t & 7;           // edge slot 0..7
    int n = blockIdx.x * 32 + g;
    if (n >= N_NODES) return;
    int s0 = rowstart[n], e0 = rowend[n];
    float4 a0 = make_float4(0.f, 0.f, 0.f, 0.f);
    float4 a1 = a0, a2 = a0, a3 = a0;
    int j = s0 + q;
    for (; j + 24 < e0; j += 32) {
        int i0 = adj[j], i1 = adj[j + 8], i2 = adj[j + 16], i3 = adj[j + 24];
        float4 v0 = xs4[i0], v1 = xs4[i1], v2 = xs4[i2], v3 = xs4[i3];
        a0.x += v0.x; a0.y += v0.y; a0.z += v0.z; a0.w += v0.w;
        a1.x += v1.x; a1.y += v1.y; a1.z += v1.z; a1.w += v1.w;
        a2.x += v2.x; a2.y += v2.y; a2.z += v2.z; a2.w += v2.w;
        a3.x += v3.x; a3.y += v3.y; a3.z += v3.z; a3.w += v3.w;
    }
    for (; j < e0; j += 8) {
        float4 v = xs4[adj[j]];
        a0.x += v.x; a0.y += v.y; a0.z += v.z; a0.w += v.w;
    }
    float4 acc;
    acc.x = (a0.x + a1.x) + (a2.x + a3.x);
    acc.y = (a0.y + a1.y) + (a2.y + a3.y);
    acc.z = (a0.z + a1.z) + (a2.z + a3.z);
    acc.w = (a0.w + a1.w) + (a2.w + a3.w);
#pragma unroll
    for (int off = 1; off <= 4; off <<= 1) {
        acc.x += __shfl_xor(acc.x, off, 64);
        acc.y += __shfl_xor(acc.y, off, 64);
        acc.z += __shfl_xor(acc.z, off, 64);
        acc.w += __shfl_xor(acc.w, off, 64);
    }
    if (q == 0) {
        float4 self = xs4[n];
        float di = dinv[n];
        float4 o;
        o.x = tanhf(di * (acc.x + self.x) + b[0]);
        o.y = tanhf(di * (acc.y + self.y) + b[1]);
        o.z = tanhf(di * (acc.z + self.z) + b[2]);
        o.w = tanhf(di * (acc.w + self.w) + b[3]);
        float p0 = o.x * W3[0] + o.y * W3[2] + o.z * W3[4] + o.w * W3[6];
        float p1 = o.x * W3[1] + o.y * W3[3] + o.z * W3[5] + o.w * W3[7];
        ((float2*)xs3)[n] = make_float2(p0 * di, p1 * di);
    }
}

// Layer-3 pull (F=2) fused with h3 write and 2->8 classifier.
__global__ __launch_bounds__(256) void k_pull_final(const float* __restrict__ xs,
                                                    const int* __restrict__ adj,
                                                    const int* __restrict__ rowstart,
                                                    const int* __restrict__ rowend,
                                                    const float* __restrict__ dinv,
                                                    const float* __restrict__ b3,
                                                    const float* __restrict__ Wc,
                                                    const float* __restrict__ bc,
                                                    float* __restrict__ out,
                                                    float* __restrict__ h3out) {
    const float2* xs2 = (const float2*)xs;
    int t = threadIdx.x;
    int g = t >> 3;          // node within block (32 nodes/block)
    int q = t & 7;           // edge slot 0..7
    int n = blockIdx.x * 32 + g;
    if (n >= N_NODES) return;
    int s0 = rowstart[n], e0 = rowend[n];
    float2 a0 = make_float2(0.f, 0.f), a1 = a0, a2 = a0, a3 = a0;
    int j = s0 + q;
    for (; j + 24 < e0; j += 32) {
        int i0 = adj[j], i1 = adj[j + 8], i2 = adj[j + 16], i3 = adj[j + 24];
        float2 v0 = xs2[i0], v1 = xs2[i1], v2 = xs2[i2], v3 = xs2[i3];
        a0.x += v0.x; a0.y += v0.y;
        a1.x += v1.x; a1.y += v1.y;
        a2.x += v2.x; a2.y += v2.y;
        a3.x += v3.x; a3.y += v3.y;
    }
    for (; j < e0; j += 8) {
        float2 v = xs2[adj[j]];
        a0.x += v.x; a0.y += v.y;
    }
    float2 acc;
    acc.x = (a0.x + a1.x) + (a2.x + a3.x);
    acc.y = (a0.y + a1.y) + (a2.y + a3.y);
#pragma unroll
    for (int off = 1; off <= 4; off <<= 1) {
        acc.x += __shfl_xor(acc.x, off, 64);
        acc.y += __shfl_xor(acc.y, off, 64);
    }
    float va = 0.f, vb = 0.f;
    if (q == 0) {
        float2 self = xs2[n];
        float di = dinv[n];
        va = tanhf(di * (acc.x + self.x) + b3[0]);
        vb = tanhf(di * (acc.y + self.y) + b3[1]);
        ((float2*)h3out)[n] = make_float2(va, vb);
    }
    int gb = (t & 63) & ~7;
    float a0b = __shfl(va, gb, 64);
    float a1b = __shfl(vb, gb, 64);
    out[8 * n + q] = a0b * Wc[q] + a1b * Wc[8 + q] + bc[q];
}

// ---------------------------------------------------------------------------
// Atomic fallback (R4 pipeline) — only if ws is unexpectedly small
template <int F>
__global__ __launch_bounds__(256) void k_scatter(const int* __restrict__ src32,
                                                 const long long* __restrict__ src64,
                                                 const int* __restrict__ dst32,
                                                 const long long* __restrict__ dst64,
                                                 const int* __restrict__ flag,
                                                 const float* __restrict__ xs,
                                                 float* __restrict__ acc) {
    long long gid = (long long)blockIdx.x * 256 + threadIdx.x;
    int e = (int)(gid / F), f = (int)(gid % F);
    if (e < N_EDGES) {
        int is64 = *flag;
        unsigned s = load_idx(src32, src64, is64, e);
        unsigned d = load_idx(dst32, dst64, is64, e);
        if (s < N_NODES && d < N_NODES)
            atomicAdd(&acc[d * F + f], xs[s * F + f]);
    }
}
__global__ __launch_bounds__(256) void k_deg_init(float* __restrict__ deg) {
    int i = blockIdx.x * 256 + threadIdx.x;
    if (i < N_NODES) deg[i] = 1.0f;
}
__global__ __launch_bounds__(256) void k_deg_count(const int* __restrict__ dst32,
                                                   const long long* __restrict__ dst64,
                                                   const int* __restrict__ flag,
                                                   float* __restrict__ deg) {
    int e = blockIdx.x * 256 + threadIdx.x;
    if (e < N_EDGES) {
        unsigned d = load_idx(dst32, dst64, *flag, e);
        if (d < N_NODES) atomicAdd(&deg[d], 1.0f);
    }
}
__global__ __launch_bounds__(256) void k_rsqrt(float* __restrict__ deg) {
    int i = blockIdx.x * 256 + threadIdx.x;
    if (i < N_NODES) deg[i] = rsqrtf(deg[i]);
}
template <int F>
__global__ __launch_bounds__(256) void k_finish(const float* __restrict__ acc,
                                                const float* __restrict__ dinv,
                                                const float* __restrict__ b,
                                                float* __restrict__ out) {
    int i = blockIdx.x * 256 + threadIdx.x;
    if (i >= N_NODES * F) return;
    int n = i / F, f = i % F;
    out[i] = tanhf(dinv[n] * acc[i] + b[f]);
}
__global__ __launch_bounds__(256) void k_final(const float* __restrict__ acc3,
                                               const float* __restrict__ dinv,
                                               const float* __restrict__ b3,
                                               const float* __restrict__ Wc,
                                               const float* __restrict__ bc,
                                               float* __restrict__ out,
                                               float* __restrict__ h3out) {
    int n = blockIdx.x * 256 + threadIdx.x;
    if (n >= N_NODES) return;
    float di = dinv[n];
    float a0 = tanhf(di * acc3[2 * n + 0] + b3[0]);
    float a1 = tanhf(di * acc3[2 * n + 1] + b3[1]);
    h3out[2 * n + 0] = a0;
    h3out[2 * n + 1] = a1;
#pragma unroll
    for (int c = 0; c < 8; c++)
        out[8 * n + c] = a0 * Wc[c] + a1 * Wc[8 + c] + bc[c];
}
__global__ __launch_bounds__(256) void k_zero_out(float* __restrict__ out, int n) {
    int i = blockIdx.x * 256 + threadIdx.x;
    if (i < n) out[i] = 0.0f;
}

// ---------------------------------------------------------------------------
extern "C" void kernel_launch(void* const* d_in, const int* in_sizes, int n_in,
                              void* d_out, int out_size, void* d_ws, size_t ws_size,
                              hipStream_t stream) {
    float* out = (float*)d_out;
    const float* h   = (const float*)d_in[0];
    const void*  ei  = d_in[1];
    const float* W1  = (const float*)d_in[2];
    const float* b1  = (const float*)d_in[3];
    const float* W2  = (const float*)d_in[4];
    const float* b2  = (const float*)d_in[5];
    const float* W3  = (const float*)d_in[6];
    const float* b3  = (const float*)d_in[7];
    const float* Wc  = (const float*)d_in[8];
    const float* bc  = (const float*)d_in[9];

    const int*       src32 = (const int*)ei;
    const int*       dst32 = src32 + N_EDGES;
    const long long* src64 = (const long long*)ei;
    const long long* dst64 = src64 + N_EDGES;

    float* h3out = out + 8 * N_NODES;
    const int NB_E = (N_EDGES + 255) / 256;

    if (d_ws != nullptr && ws_size >= NEW_WS_BYTES) {
        // ---------------- multisplit CSR + pull path ----------------
        float* dinv    = (float*)d_ws;               // N
        int* rowstart  = (int*)(dinv + N_NODES);     // N
        int* rowend    = rowstart + N_NODES;         // N
        int* adj       = rowend + N_NODES;           // E
        int* S         = adj + N_EDGES;              // 32N == E words, shared
        float* xsA     = (float*)S;                  // 16N (after build)
        float* xsB     = xsA + 16 * N_NODES;         // 16N
        int* P         = S;                          // E (during build)
        int* cmat      = adj;                        // NBUCK*NBLKA <= E, dead before adj written
        int* bt        = S + 3200000;                // NBUCK+1
        int* bt2       = bt + NBUCK + 1;             // NBUCK+1
        int* flag      = bt2 + NBUCK + 1;            // 1

        // --- build: try single cooperative kernel, fall back to 6-kernel path
        {
            const int* a_src32 = src32; const long long* a_src64 = src64;
            const int* a_dst32 = dst32; const long long* a_dst64 = dst64;
            int* a_cmat = cmat; int* a_bt = bt; int* a_bt2 = bt2; int* a_P = P;
            void* args[] = {(void*)&a_src32, (void*)&a_src64,
                            (void*)&a_dst32, (void*)&a_dst64,
                            (void*)&a_cmat, (void*)&a_bt, (void*)&a_bt2,
                            (void*)&a_P};
            hipError_t e = hipLaunchCooperativeKernel(
                (void*)k_build_graph, dim3(NBLKA), dim3(1024), args, 0, stream);
            if (e == hipSuccess) {
                k_bbuild<<<NBUCK, 512, 0, stream>>>(P, bt2, adj, rowstart, rowend, dinv);
            } else {
                k_detect_i64<<<1, 64, 0, stream>>>(src32, flag);
                k_bcount<<<NBLKA, BBA, 0, stream>>>(dst32, dst64, flag, cmat);
                k_bsum<<<NBUCK, 256, 0, stream>>>(cmat, bt);
                k_btscan<<<1, 512, 0, stream>>>(bt);
                k_boffs<<<NBUCK, 256, 0, stream>>>(cmat, bt);
                k_bscatter<<<NBLKA, BBA, 0, stream>>>(src32, src64, dst32, dst64, flag, cmat, P);
                k_bbuild<<<NBUCK, 512, 0, stream>>>(P, bt, adj, rowstart, rowend, dinv);
            }
        }

        // layer 1: 128 -> 16   (xsA overwrites P — P dead after k_bbuild)
        k_gemm1<<<N_NODES / 16, 256, 0, stream>>>(h, W1, dinv, xsA, xsA);
        // pull-1 fused with layer-2 GEMM: writes xs2 into xsB (4N)
        k_pull16g2<<<(N_NODES + 15) / 16, 256, 0, stream>>>(
            xsA, adj, rowstart, rowend, dinv, b1, W2, xsB);
        // pull-2 fused with layer-3 GEMM: writes xs3 into xsA (2N; xs1 dead)
        k_pull4g3<<<(N_NODES + 31) / 32, 256, 0, stream>>>(
            xsB, adj, rowstart, rowend, dinv, b2, W3, xsA);
        // pull-3 fused with classifier
        k_pull_final<<<(N_NODES + 31) / 32, 256, 0, stream>>>(
            xsA, adj, rowstart, rowend, dinv, b3, Wc, bc, out, h3out);
        return;
    }

    if (d_ws != nullptr && ws_size >= ATOMIC_WS_BYTES) {
        // ---------------- atomic fallback (R4) ----------------
        float* ws   = (float*)d_ws;
        float* dinv = ws;
        float* bufA = dinv + N_NODES;
        float* bufB = bufA + 16 * N_NODES;
        int*   flag = (int*)(bufB + 16 * N_NODES);
        float* xs1 = bufA, *acc1 = bufB, *h1 = bufA;
        float* xs2 = bufB, *acc2 = bufB + 4 * N_NODES, *h2 = bufA;
        float* xs3 = bufB, *acc3 = bufB + 2 * N_NODES;

        k_detect_i64<<<1, 64, 0, stream>>>(src32, flag);
        k_deg_init<<<NB_BLK, 256, 0, stream>>>(dinv);
        k_deg_count<<<NB_E, 256, 0, stream>>>(dst32, dst64, flag, dinv);
        k_rsqrt<<<NB_BLK, 256, 0, stream>>>(dinv);
        k_gemm1<<<N_NODES / 16, 256, 0, stream>>>(h, W1, dinv, xs1, acc1);
        k_scatter<16><<<(int)(((long long)N_EDGES * 16 + 255) / 256), 256, 0, stream>>>(
            src32, src64, dst32, dst64, flag, xs1, acc1);
        k_finish<16><<<(N_NODES * 16 + 255) / 256, 256, 0, stream>>>(acc1, dinv, b1, h1);
        k_gemm_small<16, 4><<<(N_NODES * 4 + 255) / 256, 256, 0, stream>>>(h1, W2, dinv, xs2, acc2);
        k_scatter<4><<<(int)(((long long)N_EDGES * 4 + 255) / 256), 256, 0, stream>>>(
            src32, src64, dst32, dst64, flag, xs2, acc2);
        k_finish<4><<<(N_NODES * 4 + 255) / 256, 256, 0, stream>>>(acc2, dinv, b2, h2);
        k_gemm_small<4, 2><<<(N_NODES * 2 + 255) / 256, 256, 0, stream>>>(h2, W3, dinv, xs3, acc3);
        k_scatter<2><<<(int)(((long long)N_EDGES * 2 + 255) / 256), 256, 0, stream>>>(
            src32, src64, dst32, dst64, flag, xs3, acc3);
        k_final<<<NB_BLK, 256, 0, stream>>>(acc3, dinv, b3, Wc, bc, out, h3out);
        return;
    }

    k_zero_out<<<(out_size + 255) / 256, 256, 0, stream>>>(out, out_size);
}

// Round 9
// 257.187 us; speedup vs baseline: 1.3956x; 1.3956x over previous
//
#include <hip/hip_runtime.h>
#include <math.h>

#define N_NODES 100000
#define N_EDGES 3200000
#define NPB    256                               // nodes per bucket
#define NBUCK  ((N_NODES + NPB - 1) / NPB)       // 391
#define NBLKA  256                               // pass-A blocks (region granularity!)
#define BBA    1024                              // pass-A block size (occupancy)
#define EPB    ((N_EDGES + NBLKA - 1) / NBLKA)   // 12500
#define NB_BLK ((N_NODES + 255) / 256)

// ws words: dinv N + rowstart N + rowend N + adj E + S max(32N,E)
//           + bt (NBUCK+1) + bt2 (NBUCK+1) + flag.
//           cmat (NBUCK*NBLKA = 100096) ALIASES adj (dead before adj written).
#define NEW_WS_WORDS (3u*N_NODES + N_EDGES + 3200000u + 2u*(NBUCK + 1u) + 2u)
#define NEW_WS_BYTES (NEW_WS_WORDS * 4u)
// atomic fallback path (R4): 33N floats + flag
#define ATOMIC_WS_BYTES ((33u*N_NODES + 16u) * 4u)

// ---------------------------------------------------------------------------
// dtype probe + bt zeroing (bt totals are accumulated by k_bcount atomics).
__global__ __launch_bounds__(256) void k_detect_i64(const int* __restrict__ ei_words,
                                                    int* __restrict__ flag,
                                                    int* __restrict__ bt) {
    int t = threadIdx.x;
    for (int i = t; i < NBUCK + 1; i += 256) bt[i] = 0;
    if (t == 0) {
        int allzero = 1;
        for (int i = 0; i < 64; i++)
            if (ei_words[2 * i + 1] != 0) allzero = 0;
        *flag = allzero;  // 1 => int64 layout
    }
}

__device__ __forceinline__ unsigned load_idx(const int* p32, const long long* p64,
                                             int is64, int e) {
    return is64 ? (unsigned)(unsigned long long)p64[e] : (unsigned)p32[e];
}

// ---------------------------------------------------------------------------
// Pass A1: per-(block, bucket) edge counts -> cmat[blk*NBUCK + b] (coalesced)
// and bucket totals via global atomics (replaces k_bsum).
__global__ __launch_bounds__(BBA) void k_bcount(const int* __restrict__ dst32,
                                                const long long* __restrict__ dst64,
                                                const int* __restrict__ flag,
                                                int* __restrict__ cmat,
                                                int* __restrict__ bt) {
    __shared__ int lc[NBUCK];
    int t = threadIdx.x, blk = blockIdx.x;
    for (int i = t; i < NBUCK; i += BBA) lc[i] = 0;
    __syncthreads();
    int is64 = *flag;
    int e0 = blk * EPB;
    int e1 = e0 + EPB; if (e1 > N_EDGES) e1 = N_EDGES;
    for (int e = e0 + t; e < e1; e += BBA) {
        unsigned d = load_idx(dst32, dst64, is64, e);
        if (d < N_NODES) atomicAdd(&lc[d >> 8], 1);
    }
    __syncthreads();
    for (int b = t; b < NBUCK; b += BBA) {
        int v = lc[b];
        cmat[blk * NBUCK + b] = v;
        if (v) atomicAdd(&bt[b], v);
    }
}

// Pass A2: per-bucket column scan of cmat + inline full bucket-prefix scan
// (replaces k_btscan + k_boffs). Block 0 publishes the prefix to bt2.
__global__ __launch_bounds__(512) void k_boffs2(int* __restrict__ cmat,
                                                const int* __restrict__ bt,
                                                int* __restrict__ bt2) {
    __shared__ int s[512];
    __shared__ int cs[256];
    int b = blockIdx.x, t = threadIdx.x;
    s[t] = (t < NBUCK) ? bt[t] : 0;
    __syncthreads();
    for (int off = 1; off < 512; off <<= 1) {
        int v = (t >= off) ? s[t - off] : 0;
        __syncthreads();
        s[t] += v;
        __syncthreads();
    }
    int prefb = (b == 0) ? 0 : s[b - 1];
    if (b == 0) {
        if (t < NBUCK) bt2[t] = (t == 0) ? 0 : s[t - 1];
        if (t == 0) bt2[NBUCK] = s[NBUCK - 1];
    }
    if (t < 256) cs[t] = cmat[t * NBUCK + b];
    __syncthreads();
    for (int off = 1; off < 256; off <<= 1) {
        int v = (t < 256 && t >= off) ? cs[t - off] : 0;
        __syncthreads();
        if (t < 256) cs[t] += v;
        __syncthreads();
    }
    if (t < 256) cmat[t * NBUCK + b] = ((t == 0) ? 0 : cs[t - 1]) + prefb;
}

// Pass A3: scatter packed entries (dstLow<<17 | src) into bucket-major P.
__global__ __launch_bounds__(BBA) void k_bscatter(const int* __restrict__ src32,
                                                  const long long* __restrict__ src64,
                                                  const int* __restrict__ dst32,
                                                  const long long* __restrict__ dst64,
                                                  const int* __restrict__ flag,
                                                  const int* __restrict__ cmat,
                                                  int* __restrict__ P) {
    __shared__ int cur[NBUCK];
    int t = threadIdx.x, blk = blockIdx.x;
    for (int i = t; i < NBUCK; i += BBA) cur[i] = cmat[blk * NBUCK + i];
    __syncthreads();
    int is64 = *flag;
    int e0 = blk * EPB;
    int e1 = e0 + EPB; if (e1 > N_EDGES) e1 = N_EDGES;
    for (int e = e0 + t; e < e1; e += BBA) {
        unsigned d = load_idx(dst32, dst64, is64, e);
        if (d < N_NODES) {
            unsigned s = load_idx(src32, src64, is64, e);
            int pos = atomicAdd(&cur[d >> 8], 1);
            P[pos] = (int)(((d & 255u) << 17) | (s & 0x1FFFFu));
        }
    }
}

// Pass B: per-bucket CSR build (one 512-thread block per 256-node bucket).
__global__ __launch_bounds__(512) void k_bbuild(const int* __restrict__ P,
                                                const int* __restrict__ bt,
                                                int* __restrict__ adj,
                                                int* __restrict__ rowstart,
                                                int* __restrict__ rowend,
                                                float* __restrict__ dinv) {
    __shared__ int cnt[NPB];
    __shared__ int s[NPB];
    int b = blockIdx.x, t = threadIdx.x;
    int bo = bt[b], be = bt[b + 1];
    if (t < NPB) cnt[t] = 0;
    __syncthreads();
    for (int i = bo + t; i < be; i += 512) atomicAdd(&cnt[P[i] >> 17], 1);
    __syncthreads();
    if (t < NPB) s[t] = cnt[t];
    __syncthreads();
    for (int off = 1; off < NPB; off <<= 1) {
        int v = (t >= off && t < NPB) ? s[t - off] : 0;
        __syncthreads();
        if (t < NPB) s[t] += v;
        __syncthreads();
    }
    int ex = (t == 0 || t >= NPB) ? 0 : s[t - 1];
    int node = b * NPB + t;
    if (t < NPB && node < N_NODES) {
        rowstart[node] = bo + ex;
        rowend[node]   = bo + ex + cnt[t];
        dinv[node]     = rsqrtf((float)cnt[t] + 1.0f);
    }
    __syncthreads();
    if (t < NPB) s[t] = ex;  // cursors
    __syncthreads();
    for (int i = bo + t; i < be; i += 512) {
        int ent = P[i];
        int pos = bo + atomicAdd(&s[ent >> 17], 1);
        adj[pos] = ent & 0x1FFFF;
    }
}

// ---------------------------------------------------------------------------
// Layer-1 GEMM (R6-proven anchor): 16 nodes/block, lane = (node, f).
__global__ __launch_bounds__(256) void k_gemm1(const float* __restrict__ h,
                                               const float* __restrict__ W,
                                               const float* __restrict__ dinv,
                                               float* __restrict__ xs,
                                               float* acc) {
    __shared__ float Wt[16 * 132];
    __shared__ float Hs[16 * 132];
    int tid = threadIdx.x;
    for (int i = tid; i < 2048; i += 256) {
        int k = i >> 4, f = i & 15;
        Wt[f * 132 + k] = W[i];
    }
    int nodeBase = blockIdx.x * 16;
    for (int i = tid; i < 512; i += 256) {
        int r = i >> 5, c = i & 31;
        float4 v = ((const float4*)(h + (size_t)(nodeBase + r) * 128))[c];
        *((float4*)&Hs[r * 132 + c * 4]) = v;
    }
    __syncthreads();
    int nl = tid >> 4;
    int f  = tid & 15;
    int n  = nodeBase + nl;
    const float* hr = &Hs[nl * 132];
    const float* wr = &Wt[f * 132];
    float s = 0.0f;
#pragma unroll
    for (int k = 0; k < 128; k++) s += hr[k] * wr[k];
    s *= dinv[n];
    xs[n * 16 + f]  = s;
    acc[n * 16 + f] = s;
}

template <int FI, int FO>
__global__ __launch_bounds__(256) void k_gemm_small(const float* __restrict__ x,
                                                    const float* __restrict__ W,
                                                    const float* __restrict__ dinv,
                                                    float* __restrict__ xs,
                                                    float* acc) {
    int i = blockIdx.x * 256 + threadIdx.x;
    if (i >= N_NODES * FO) return;
    int n = i / FO, f = i % FO;
    float s = 0.0f;
#pragma unroll
    for (int k = 0; k < FI; k++) s += x[n * FI + k] * W[k * FO + f];
    s *= dinv[n];
    xs[i] = s;
    acc[i] = s;
}

// ---------------------------------------------------------------------------
// Pull F=16 fused with layer-2 GEMM.
__global__ __launch_bounds__(256) void k_pull16g2(const float* __restrict__ xs,
                                                  const int* __restrict__ adj,
                                                  const int* __restrict__ rowstart,
                                                  const int* __restrict__ rowend,
                                                  const float* __restrict__ dinv,
                                                  const float* __restrict__ b,
                                                  const float* __restrict__ W2,
                                                  float* __restrict__ xs2) {
    const float4* xs4 = (const float4*)xs;
    int t = threadIdx.x;
    int g = t >> 4;          // node within block (16 nodes/block)
    int q = t & 15;
    int fv = q & 3;          // which float4 of the 16-float row
    int k  = q >> 2;         // edge slot 0..3
    int n = blockIdx.x * 16 + g;
    if (n >= N_NODES) return;
    int s0 = rowstart[n], e0 = rowend[n];
    float4 a0 = make_float4(0.f, 0.f, 0.f, 0.f);
    float4 a1 = a0, a2 = a0, a3 = a0;
    int j = s0 + k;
    for (; j + 12 < e0; j += 16) {
        int i0 = adj[j], i1 = adj[j + 4], i2 = adj[j + 8], i3 = adj[j + 12];
        float4 v0 = xs4[i0 * 4 + fv];
        float4 v1 = xs4[i1 * 4 + fv];
        float4 v2 = xs4[i2 * 4 + fv];
        float4 v3 = xs4[i3 * 4 + fv];
        a0.x += v0.x; a0.y += v0.y; a0.z += v0.z; a0.w += v0.w;
        a1.x += v1.x; a1.y += v1.y; a1.z += v1.z; a1.w += v1.w;
        a2.x += v2.x; a2.y += v2.y; a2.z += v2.z; a2.w += v2.w;
        a3.x += v3.x; a3.y += v3.y; a3.z += v3.z; a3.w += v3.w;
    }
    for (; j < e0; j += 4) {
        float4 v = xs4[adj[j] * 4 + fv];
        a0.x += v.x; a0.y += v.y; a0.z += v.z; a0.w += v.w;
    }
    float4 acc;
    acc.x = (a0.x + a1.x) + (a2.x + a3.x);
    acc.y = (a0.y + a1.y) + (a2.y + a3.y);
    acc.z = (a0.z + a1.z) + (a2.z + a3.z);
    acc.w = (a0.w + a1.w) + (a2.w + a3.w);
#pragma unroll
    for (int off = 4; off <= 8; off <<= 1) {
        acc.x += __shfl_xor(acc.x, off, 64);
        acc.y += __shfl_xor(acc.y, off, 64);
        acc.z += __shfl_xor(acc.z, off, 64);
        acc.w += __shfl_xor(acc.w, off, 64);
    }
    if (k == 0) {
        float4 self = xs4[n * 4 + fv];
        float di = dinv[n];
        float4 bb = ((const float4*)b)[fv];
        float4 o;
        o.x = tanhf(di * (acc.x + self.x) + bb.x);
        o.y = tanhf(di * (acc.y + self.y) + bb.y);
        o.z = tanhf(di * (acc.z + self.z) + bb.z);
        o.w = tanhf(di * (acc.w + self.w) + bb.w);
        const float4* W2r = (const float4*)W2;
        float4 w0 = W2r[4 * fv + 0], w1 = W2r[4 * fv + 1];
        float4 w2 = W2r[4 * fv + 2], w3 = W2r[4 * fv + 3];
        float4 p;
        p.x = o.x * w0.x + o.y * w1.x + o.z * w2.x + o.w * w3.x;
        p.y = o.x * w0.y + o.y * w1.y + o.z * w2.y + o.w * w3.y;
        p.z = o.x * w0.z + o.y * w1.z + o.z * w2.z + o.w * w3.z;
        p.w = o.x * w0.w + o.y * w1.w + o.z * w2.w + o.w * w3.w;
        p.x += __shfl_xor(p.x, 1, 64); p.x += __shfl_xor(p.x, 2, 64);
        p.y += __shfl_xor(p.y, 1, 64); p.y += __shfl_xor(p.y, 2, 64);
        p.z += __shfl_xor(p.z, 1, 64); p.z += __shfl_xor(p.z, 2, 64);
        p.w += __shfl_xor(p.w, 1, 64); p.w += __shfl_xor(p.w, 2, 64);
        float pv = (fv == 0) ? p.x : (fv == 1) ? p.y : (fv == 2) ? p.z : p.w;
        xs2[n * 4 + fv] = pv * di;
    }
}

// Pull F=4 fused with layer-3 GEMM.
__global__ __launch_bounds__(256) void k_pull4g3(const float* __restrict__ xs,
                                                 const int* __restrict__ adj,
                                                 const int* __restrict__ rowstart,
                                                 const int* __restrict__ rowend,
                                                 const float* __restrict__ dinv,
                                                 const float* __restrict__ b,
                                                 const float* __restrict__ W3,
                                                 float* __restrict__ xs3) {
    const float4* xs4 = (const float4*)xs;
    int t = threadIdx.x;
    int g = t >> 3;          // node within block (32 nodes/block)
    int q = t & 7;           // edge slot 0..7
    int n = blockIdx.x * 32 + g;
    if (n >= N_NODES) return;
    int s0 = rowstart[n], e0 = rowend[n];
    float4 a0 = make_float4(0.f, 0.f, 0.f, 0.f);
    float4 a1 = a0, a2 = a0, a3 = a0;
    int j = s0 + q;
    for (; j + 24 < e0; j += 32) {
        int i0 = adj[j], i1 = adj[j + 8], i2 = adj[j + 16], i3 = adj[j + 24];
        float4 v0 = xs4[i0], v1 = xs4[i1], v2 = xs4[i2], v3 = xs4[i3];
        a0.x += v0.x; a0.y += v0.y; a0.z += v0.z; a0.w += v0.w;
        a1.x += v1.x; a1.y += v1.y; a1.z += v1.z; a1.w += v1.w;
        a2.x += v2.x; a2.y += v2.y; a2.z += v2.z; a2.w += v2.w;
        a3.x += v3.x; a3.y += v3.y; a3.z += v3.z; a3.w += v3.w;
    }
    for (; j < e0; j += 8) {
        float4 v = xs4[adj[j]];
        a0.x += v.x; a0.y += v.y; a0.z += v.z; a0.w += v.w;
    }
    float4 acc;
    acc.x = (a0.x + a1.x) + (a2.x + a3.x);
    acc.y = (a0.y + a1.y) + (a2.y + a3.y);
    acc.z = (a0.z + a1.z) + (a2.z + a3.z);
    acc.w = (a0.w + a1.w) + (a2.w + a3.w);
#pragma unroll
    for (int off = 1; off <= 4; off <<= 1) {
        acc.x += __shfl_xor(acc.x, off, 64);
        acc.y += __shfl_xor(acc.y, off, 64);
        acc.z += __shfl_xor(acc.z, off, 64);
        acc.w += __shfl_xor(acc.w, off, 64);
    }
    if (q == 0) {
        float4 self = xs4[n];
        float di = dinv[n];
        float4 o;
        o.x = tanhf(di * (acc.x + self.x) + b[0]);
        o.y = tanhf(di * (acc.y + self.y) + b[1]);
        o.z = tanhf(di * (acc.z + self.z) + b[2]);
        o.w = tanhf(di * (acc.w + self.w) + b[3]);
        float p0 = o.x * W3[0] + o.y * W3[2] + o.z * W3[4] + o.w * W3[6];
        float p1 = o.x * W3[1] + o.y * W3[3] + o.z * W3[5] + o.w * W3[7];
        ((float2*)xs3)[n] = make_float2(p0 * di, p1 * di);
    }
}

// Layer-3 pull (F=2) fused with h3 write and 2->8 classifier.
__global__ __launch_bounds__(256) void k_pull_final(const float* __restrict__ xs,
                                                    const int* __restrict__ adj,
                                                    const int* __restrict__ rowstart,
                                                    const int* __restrict__ rowend,
                                                    const float* __restrict__ dinv,
                                                    const float* __restrict__ b3,
                                                    const float* __restrict__ Wc,
                                                    const float* __restrict__ bc,
                                                    float* __restrict__ out,
                                                    float* __restrict__ h3out) {
    const float2* xs2 = (const float2*)xs;
    int t = threadIdx.x;
    int g = t >> 3;          // node within block (32 nodes/block)
    int q = t & 7;           // edge slot 0..7
    int n = blockIdx.x * 32 + g;
    if (n >= N_NODES) return;
    int s0 = rowstart[n], e0 = rowend[n];
    float2 a0 = make_float2(0.f, 0.f), a1 = a0, a2 = a0, a3 = a0;
    int j = s0 + q;
    for (; j + 24 < e0; j += 32) {
        int i0 = adj[j], i1 = adj[j + 8], i2 = adj[j + 16], i3 = adj[j + 24];
        float2 v0 = xs2[i0], v1 = xs2[i1], v2 = xs2[i2], v3 = xs2[i3];
        a0.x += v0.x; a0.y += v0.y;
        a1.x += v1.x; a1.y += v1.y;
        a2.x += v2.x; a2.y += v2.y;
        a3.x += v3.x; a3.y += v3.y;
    }
    for (; j < e0; j += 8) {
        float2 v = xs2[adj[j]];
        a0.x += v.x; a0.y += v.y;
    }
    float2 acc;
    acc.x = (a0.x + a1.x) + (a2.x + a3.x);
    acc.y = (a0.y + a1.y) + (a2.y + a3.y);
#pragma unroll
    for (int off = 1; off <= 4; off <<= 1) {
        acc.x += __shfl_xor(acc.x, off, 64);
        acc.y += __shfl_xor(acc.y, off, 64);
    }
    float va = 0.f, vb = 0.f;
    if (q == 0) {
        float2 self = xs2[n];
        float di = dinv[n];
        va = tanhf(di * (acc.x + self.x) + b3[0]);
        vb = tanhf(di * (acc.y + self.y) + b3[1]);
        ((float2*)h3out)[n] = make_float2(va, vb);
    }
    int gb = (t & 63) & ~7;
    float a0b = __shfl(va, gb, 64);
    float a1b = __shfl(vb, gb, 64);
    out[8 * n + q] = a0b * Wc[q] + a1b * Wc[8 + q] + bc[q];
}

// ---------------------------------------------------------------------------
// Atomic fallback (R4 pipeline) — only if ws is unexpectedly small
template <int F>
__global__ __launch_bounds__(256) void k_scatter(const int* __restrict__ src32,
                                                 const long long* __restrict__ src64,
                                                 const int* __restrict__ dst32,
                                                 const long long* __restrict__ dst64,
                                                 const int* __restrict__ flag,
                                                 const float* __restrict__ xs,
                                                 float* __restrict__ acc) {
    long long gid = (long long)blockIdx.x * 256 + threadIdx.x;
    int e = (int)(gid / F), f = (int)(gid % F);
    if (e < N_EDGES) {
        int is64 = *flag;
        unsigned s = load_idx(src32, src64, is64, e);
        unsigned d = load_idx(dst32, dst64, is64, e);
        if (s < N_NODES && d < N_NODES)
            atomicAdd(&acc[d * F + f], xs[s * F + f]);
    }
}
__global__ __launch_bounds__(256) void k_deg_init(float* __restrict__ deg) {
    int i = blockIdx.x * 256 + threadIdx.x;
    if (i < N_NODES) deg[i] = 1.0f;
}
__global__ __launch_bounds__(256) void k_deg_count(const int* __restrict__ dst32,
                                                   const long long* __restrict__ dst64,
                                                   const int* __restrict__ flag,
                                                   float* __restrict__ deg) {
    int e = blockIdx.x * 256 + threadIdx.x;
    if (e < N_EDGES) {
        unsigned d = load_idx(dst32, dst64, *flag, e);
        if (d < N_NODES) atomicAdd(&deg[d], 1.0f);
    }
}
__global__ __launch_bounds__(256) void k_rsqrt(float* __restrict__ deg) {
    int i = blockIdx.x * 256 + threadIdx.x;
    if (i < N_NODES) deg[i] = rsqrtf(deg[i]);
}
template <int F>
__global__ __launch_bounds__(256) void k_finish(const float* __restrict__ acc,
                                                const float* __restrict__ dinv,
                                                const float* __restrict__ b,
                                                float* __restrict__ out) {
    int i = blockIdx.x * 256 + threadIdx.x;
    if (i >= N_NODES * F) return;
    int n = i / F, f = i % F;
    out[i] = tanhf(dinv[n] * acc[i] + b[f]);
}
__global__ __launch_bounds__(256) void k_final(const float* __restrict__ acc3,
                                               const float* __restrict__ dinv,
                                               const float* __restrict__ b3,
                                               const float* __restrict__ Wc,
                                               const float* __restrict__ bc,
                                               float* __restrict__ out,
                                               float* __restrict__ h3out) {
    int n = blockIdx.x * 256 + threadIdx.x;
    if (n >= N_NODES) return;
    float di = dinv[n];
    float a0 = tanhf(di * acc3[2 * n + 0] + b3[0]);
    float a1 = tanhf(di * acc3[2 * n + 1] + b3[1]);
    h3out[2 * n + 0] = a0;
    h3out[2 * n + 1] = a1;
#pragma unroll
    for (int c = 0; c < 8; c++)
        out[8 * n + c] = a0 * Wc[c] + a1 * Wc[8 + c] + bc[c];
}
__global__ __launch_bounds__(256) void k_zero_out(float* __restrict__ out, int n) {
    int i = blockIdx.x * 256 + threadIdx.x;
    if (i < n) out[i] = 0.0f;
}

// ---------------------------------------------------------------------------
extern "C" void kernel_launch(void* const* d_in, const int* in_sizes, int n_in,
                              void* d_out, int out_size, void* d_ws, size_t ws_size,
                              hipStream_t stream) {
    float* out = (float*)d_out;
    const float* h   = (const float*)d_in[0];
    const void*  ei  = d_in[1];
    const float* W1  = (const float*)d_in[2];
    const float* b1  = (const float*)d_in[3];
    const float* W2  = (const float*)d_in[4];
    const float* b2  = (const float*)d_in[5];
    const float* W3  = (const float*)d_in[6];
    const float* b3  = (const float*)d_in[7];
    const float* Wc  = (const float*)d_in[8];
    const float* bc  = (const float*)d_in[9];

    const int*       src32 = (const int*)ei;
    const int*       dst32 = src32 + N_EDGES;
    const long long* src64 = (const long long*)ei;
    const long long* dst64 = src64 + N_EDGES;

    float* h3out = out + 8 * N_NODES;
    const int NB_E = (N_EDGES + 255) / 256;

    if (d_ws != nullptr && ws_size >= NEW_WS_BYTES) {
        // ---------------- multisplit CSR + pull path ----------------
        float* dinv    = (float*)d_ws;               // N
        int* rowstart  = (int*)(dinv + N_NODES);     // N
        int* rowend    = rowstart + N_NODES;         // N
        int* adj       = rowend + N_NODES;           // E
        int* S         = adj + N_EDGES;              // 32N == E words, shared
        float* xsA     = (float*)S;                  // 16N (after build)
        float* xsB     = xsA + 16 * N_NODES;         // 16N
        int* P         = S;                          // E (during build)
        int* cmat      = adj;                        // NBUCK*NBLKA <= E, dead before adj written
        int* bt        = S + 3200000;                // NBUCK+1 (totals)
        int* bt2       = bt + NBUCK + 1;             // NBUCK+1 (prefix)
        int* flag      = bt2 + NBUCK + 1;            // 1

        k_detect_i64<<<1, 256, 0, stream>>>(src32, flag, bt);
        k_bcount<<<NBLKA, BBA, 0, stream>>>(dst32, dst64, flag, cmat, bt);
        k_boffs2<<<NBUCK, 512, 0, stream>>>(cmat, bt, bt2);
        k_bscatter<<<NBLKA, BBA, 0, stream>>>(src32, src64, dst32, dst64, flag, cmat, P);
        k_bbuild<<<NBUCK, 512, 0, stream>>>(P, bt2, adj, rowstart, rowend, dinv);

        // layer 1: 128 -> 16   (xsA overwrites P — P dead after k_bbuild)
        k_gemm1<<<N_NODES / 16, 256, 0, stream>>>(h, W1, dinv, xsA, xsA);
        // pull-1 fused with layer-2 GEMM: writes xs2 into xsB (4N)
        k_pull16g2<<<(N_NODES + 15) / 16, 256, 0, stream>>>(
            xsA, adj, rowstart, rowend, dinv, b1, W2, xsB);
        // pull-2 fused with layer-3 GEMM: writes xs3 into xsA (2N; xs1 dead)
        k_pull4g3<<<(N_NODES + 31) / 32, 256, 0, stream>>>(
            xsB, adj, rowstart, rowend, dinv, b2, W3, xsA);
        // pull-3 fused with classifier
        k_pull_final<<<(N_NODES + 31) / 32, 256, 0, stream>>>(
            xsA, adj, rowstart, rowend, dinv, b3, Wc, bc, out, h3out);
        return;
    }

    if (d_ws != nullptr && ws_size >= ATOMIC_WS_BYTES) {
        // ---------------- atomic fallback (R4) ----------------
        float* ws   = (float*)d_ws;
        float* dinv = ws;
        float* bufA = dinv + N_NODES;
        float* bufB = bufA + 16 * N_NODES;
        int*   flag = (int*)(bufB + 16 * N_NODES);
        int*   btf  = flag + 1;
        float* xs1 = bufA, *acc1 = bufB, *h1 = bufA;
        float* xs2 = bufB, *acc2 = bufB + 4 * N_NODES, *h2 = bufA;
        float* xs3 = bufB, *acc3 = bufB + 2 * N_NODES;

        k_detect_i64<<<1, 256, 0, stream>>>(src32, flag, btf);
        k_deg_init<<<NB_BLK, 256, 0, stream>>>(dinv);
        k_deg_count<<<NB_E, 256, 0, stream>>>(dst32, dst64, flag, dinv);
        k_rsqrt<<<NB_BLK, 256, 0, stream>>>(dinv);
        k_gemm1<<<N_NODES / 16, 256, 0, stream>>>(h, W1, dinv, xs1, acc1);
        k_scatter<16><<<(int)(((long long)N_EDGES * 16 + 255) / 256), 256, 0, stream>>>(
            src32, src64, dst32, dst64, flag, xs1, acc1);
        k_finish<16><<<(N_NODES * 16 + 255) / 256, 256, 0, stream>>>(acc1, dinv, b1, h1);
        k_gemm_small<16, 4><<<(N_NODES * 4 + 255) / 256, 256, 0, stream>>>(h1, W2, dinv, xs2, acc2);
        k_scatter<4><<<(int)(((long long)N_EDGES * 4 + 255) / 256), 256, 0, stream>>>(
            src32, src64, dst32, dst64, flag, xs2, acc2);
        k_finish<4><<<(N_NODES * 4 + 255) / 256, 256, 0, stream>>>(acc2, dinv, b2, h2);
        k_gemm_small<4, 2><<<(N_NODES * 2 + 255) / 256, 256, 0, stream>>>(h2, W3, dinv, xs3, acc3);
        k_scatter<2><<<(int)(((long long)N_EDGES * 2 + 255) / 256), 256, 0, stream>>>(
            src32, src64, dst32, dst64, flag, xs3, acc3);
        k_final<<<NB_BLK, 256, 0, stream>>>(acc3, dinv, b3, Wc, bc, out, h3out);
        return;
    }

    k_zero_out<<<(out_size + 255) / 256, 256, 0, stream>>>(out, out_size);
}

// Round 10
// 246.489 us; speedup vs baseline: 1.4562x; 1.0434x over previous
//
#include <hip/hip_runtime.h>
#include <hip/hip_fp16.h>
#include <math.h>

#define N_NODES 100000
#define N_EDGES 3200000
#define NPB    256                               // nodes per bucket
#define NBUCK  ((N_NODES + NPB - 1) / NPB)       // 391
#define NBLKA  256                               // pass-A blocks (region granularity!)
#define BBA    1024                              // pass-A block size (occupancy)
#define EPB    ((N_EDGES + NBLKA - 1) / NBLKA)   // 12500
#define NB_BLK ((N_NODES + 255) / 256)

// ws words: dinv N + rowstart N + rowend N + adj E + S max(32N,E)
//           + bt (NBUCK+1) + flag.  cmat (NBUCK*NBLKA = 100096) ALIASES adj:
//           cmat dead after k_bscatter; adj first written in k_bbuild.
#define NEW_WS_WORDS (3u*N_NODES + N_EDGES + 3200000u + NBUCK + 2u)
#define NEW_WS_BYTES (NEW_WS_WORDS * 4u)
// atomic fallback path (R4): 33N floats + flag
#define ATOMIC_WS_BYTES ((33u*N_NODES + 16u) * 4u)

// ---------------------------------------------------------------------------
// dtype probe: edge_index may be int32 or raw int64 (reference uses int64).
__global__ void k_detect_i64(const int* __restrict__ ei_words, int* __restrict__ flag) {
    if (blockIdx.x == 0 && threadIdx.x == 0) {
        int allzero = 1;
        for (int i = 0; i < 64; i++)
            if (ei_words[2 * i + 1] != 0) allzero = 0;
        *flag = allzero;  // 1 => int64 layout
    }
}

__device__ __forceinline__ unsigned load_idx(const int* p32, const long long* p64,
                                             int is64, int e) {
    return is64 ? (unsigned)(unsigned long long)p64[e] : (unsigned)p32[e];
}

// ---------------------------------------------------------------------------
// Pass A1: per-(block, bucket) edge counts, cmat[blk*NBUCK + b] (coalesced).
__global__ __launch_bounds__(BBA) void k_bcount(const int* __restrict__ dst32,
                                                const long long* __restrict__ dst64,
                                                const int* __restrict__ flag,
                                                int* __restrict__ cmat) {
    __shared__ int lc[NBUCK];
    int t = threadIdx.x, blk = blockIdx.x;
    for (int i = t; i < NBUCK; i += BBA) lc[i] = 0;
    __syncthreads();
    int is64 = *flag;
    int e0 = blk * EPB;
    int e1 = e0 + EPB; if (e1 > N_EDGES) e1 = N_EDGES;
    for (int e = e0 + t; e < e1; e += BBA) {
        unsigned d = load_idx(dst32, dst64, is64, e);
        if (d < N_NODES) atomicAdd(&lc[d >> 8], 1);
    }
    __syncthreads();
    for (int b = t; b < NBUCK; b += BBA) cmat[blk * NBUCK + b] = lc[b];
}

// Pass A2: bucket totals bt[b] = sum_blk cmat[blk][b]
__global__ __launch_bounds__(256) void k_bsum(const int* __restrict__ cmat,
                                              int* __restrict__ bt) {
    int b = blockIdx.x, t = threadIdx.x;
    int v = cmat[t * NBUCK + b];
#pragma unroll
    for (int off = 32; off > 0; off >>= 1) v += __shfl_down(v, off, 64);
    __shared__ int s[4];
    if ((t & 63) == 0) s[t >> 6] = v;
    __syncthreads();
    if (t == 0) bt[b] = s[0] + s[1] + s[2] + s[3];
}

// Pass A3: exclusive scan of bt[0..NBUCK) in one block; bt[NBUCK] = total
__global__ __launch_bounds__(512) void k_btscan(int* __restrict__ bt) {
    __shared__ int s[512];
    int t = threadIdx.x;
    s[t] = (t < NBUCK) ? bt[t] : 0;
    __syncthreads();
    for (int off = 1; off < 512; off <<= 1) {
        int v = (t >= off) ? s[t - off] : 0;
        __syncthreads();
        s[t] += v;
        __syncthreads();
    }
    if (t < NBUCK) bt[t] = (t == 0) ? 0 : s[t - 1];
    if (t == 0) bt[NBUCK] = s[NBUCK - 1];
}

// Pass A4: per-bucket column scan of cmat (over blk) + bt[b], in place
__global__ __launch_bounds__(256) void k_boffs(int* __restrict__ cmat,
                                               const int* __restrict__ bt) {
    __shared__ int s[256];
    int b = blockIdx.x, t = threadIdx.x;
    s[t] = cmat[t * NBUCK + b];
    __syncthreads();
    for (int off = 1; off < 256; off <<= 1) {
        int v = (t >= off) ? s[t - off] : 0;
        __syncthreads();
        s[t] += v;
        __syncthreads();
    }
    cmat[t * NBUCK + b] = ((t == 0) ? 0 : s[t - 1]) + bt[b];
}

// Pass A5: scatter packed entries (dstLow<<17 | src) into bucket-major P.
__global__ __launch_bounds__(BBA) void k_bscatter(const int* __restrict__ src32,
                                                  const long long* __restrict__ src64,
                                                  const int* __restrict__ dst32,
                                                  const long long* __restrict__ dst64,
                                                  const int* __restrict__ flag,
                                                  const int* __restrict__ cmat,
                                                  int* __restrict__ P) {
    __shared__ int cur[NBUCK];
    int t = threadIdx.x, blk = blockIdx.x;
    for (int i = t; i < NBUCK; i += BBA) cur[i] = cmat[blk * NBUCK + i];
    __syncthreads();
    int is64 = *flag;
    int e0 = blk * EPB;
    int e1 = e0 + EPB; if (e1 > N_EDGES) e1 = N_EDGES;
    for (int e = e0 + t; e < e1; e += BBA) {
        unsigned d = load_idx(dst32, dst64, is64, e);
        if (d < N_NODES) {
            unsigned s = load_idx(src32, src64, is64, e);
            int pos = atomicAdd(&cur[d >> 8], 1);
            P[pos] = (int)(((d & 255u) << 17) | (s & 0x1FFFFu));
        }
    }
}

// Pass B: per-bucket CSR build (one 512-thread block per 256-node bucket).
__global__ __launch_bounds__(512) void k_bbuild(const int* __restrict__ P,
                                                const int* __restrict__ bt,
                                                int* __restrict__ adj,
                                                int* __restrict__ rowstart,
                                                int* __restrict__ rowend,
                                                float* __restrict__ dinv) {
    __shared__ int cnt[NPB];
    __shared__ int s[NPB];
    int b = blockIdx.x, t = threadIdx.x;
    int bo = bt[b], be = bt[b + 1];
    if (t < NPB) cnt[t] = 0;
    __syncthreads();
    for (int i = bo + t; i < be; i += 512) atomicAdd(&cnt[P[i] >> 17], 1);
    __syncthreads();
    if (t < NPB) s[t] = cnt[t];
    __syncthreads();
    for (int off = 1; off < NPB; off <<= 1) {
        int v = (t >= off && t < NPB) ? s[t - off] : 0;
        __syncthreads();
        if (t < NPB) s[t] += v;
        __syncthreads();
    }
    int ex = (t == 0 || t >= NPB) ? 0 : s[t - 1];
    int node = b * NPB + t;
    if (t < NPB && node < N_NODES) {
        rowstart[node] = bo + ex;
        rowend[node]   = bo + ex + cnt[t];
        dinv[node]     = rsqrtf((float)cnt[t] + 1.0f);
    }
    __syncthreads();
    if (t < NPB) s[t] = ex;  // cursors
    __syncthreads();
    for (int i = bo + t; i < be; i += 512) {
        int ent = P[i];
        int pos = bo + atomicAdd(&s[ent >> 17], 1);
        adj[pos] = ent & 0x1FFFF;
    }
}

// ---------------------------------------------------------------------------
// Layer-1 GEMM (R6 anchor), fp16 output: 16 nodes/block, lane = (node, f).
__global__ __launch_bounds__(256) void k_gemm1h(const float* __restrict__ h,
                                                const float* __restrict__ W,
                                                const float* __restrict__ dinv,
                                                __half* __restrict__ xs) {
    __shared__ float Wt[16 * 132];
    __shared__ float Hs[16 * 132];
    int tid = threadIdx.x;
    for (int i = tid; i < 2048; i += 256) {
        int k = i >> 4, f = i & 15;
        Wt[f * 132 + k] = W[i];
    }
    int nodeBase = blockIdx.x * 16;
    for (int i = tid; i < 512; i += 256) {
        int r = i >> 5, c = i & 31;
        float4 v = ((const float4*)(h + (size_t)(nodeBase + r) * 128))[c];
        *((float4*)&Hs[r * 132 + c * 4]) = v;
    }
    __syncthreads();
    int nl = tid >> 4;
    int f  = tid & 15;
    int n  = nodeBase + nl;
    const float* hr = &Hs[nl * 132];
    const float* wr = &Wt[f * 132];
    float s = 0.0f;
#pragma unroll
    for (int k = 0; k < 128; k++) s += hr[k] * wr[k];
    s *= dinv[n];
    xs[n * 16 + f] = __float2half(s);
}

// fp32 variant for atomic fallback path
__global__ __launch_bounds__(256) void k_gemm1(const float* __restrict__ h,
                                               const float* __restrict__ W,
                                               const float* __restrict__ dinv,
                                               float* __restrict__ xs,
                                               float* acc) {
    __shared__ float Wt[16 * 132];
    __shared__ float Hs[16 * 132];
    int tid = threadIdx.x;
    for (int i = tid; i < 2048; i += 256) {
        int k = i >> 4, f = i & 15;
        Wt[f * 132 + k] = W[i];
    }
    int nodeBase = blockIdx.x * 16;
    for (int i = tid; i < 512; i += 256) {
        int r = i >> 5, c = i & 31;
        float4 v = ((const float4*)(h + (size_t)(nodeBase + r) * 128))[c];
        *((float4*)&Hs[r * 132 + c * 4]) = v;
    }
    __syncthreads();
    int nl = tid >> 4;
    int f  = tid & 15;
    int n  = nodeBase + nl;
    const float* hr = &Hs[nl * 132];
    const float* wr = &Wt[f * 132];
    float s = 0.0f;
#pragma unroll
    for (int k = 0; k < 128; k++) s += hr[k] * wr[k];
    s *= dinv[n];
    xs[n * 16 + f]  = s;
    acc[n * 16 + f] = s;
}

template <int FI, int FO>
__global__ __launch_bounds__(256) void k_gemm_small(const float* __restrict__ x,
                                                    const float* __restrict__ W,
                                                    const float* __restrict__ dinv,
                                                    float* __restrict__ xs,
                                                    float* acc) {
    int i = blockIdx.x * 256 + threadIdx.x;
    if (i >= N_NODES * FO) return;
    int n = i / FO, f = i % FO;
    float s = 0.0f;
#pragma unroll
    for (int k = 0; k < FI; k++) s += x[n * FI + k] * W[k * FO + f];
    s *= dinv[n];
    xs[i] = s;
    acc[i] = s;
}

// ---------------------------------------------------------------------------
// Pull F=16 (fp16 xs) fused with layer-2 GEMM. Each lane gathers 4 halves (8B).
__device__ __forceinline__ float4 h4_to_f4(uint2 u) {
    __half2 lo = *(__half2*)&u.x;
    __half2 hi = *(__half2*)&u.y;
    float2 flo = __half22float2(lo), fhi = __half22float2(hi);
    return make_float4(flo.x, flo.y, fhi.x, fhi.y);
}

__global__ __launch_bounds__(256) void k_pull16g2(const __half* __restrict__ xs,
                                                  const int* __restrict__ adj,
                                                  const int* __restrict__ rowstart,
                                                  const int* __restrict__ rowend,
                                                  const float* __restrict__ dinv,
                                                  const float* __restrict__ b,
                                                  const float* __restrict__ W2,
                                                  float* __restrict__ xs2) {
    const uint2* xsh = (const uint2*)xs;   // node row = 4 x uint2 (16 halves)
    int t = threadIdx.x;
    int g = t >> 4;          // node within block (16 nodes/block)
    int q = t & 15;
    int fv = q & 3;          // which 4-half group of the 16-half row
    int k  = q >> 2;         // edge slot 0..3
    int n = blockIdx.x * 16 + g;
    if (n >= N_NODES) return;
    int s0 = rowstart[n], e0 = rowend[n];
    float4 a0 = make_float4(0.f, 0.f, 0.f, 0.f);
    float4 a1 = a0, a2 = a0, a3 = a0;
    int j = s0 + k;
    for (; j + 12 < e0; j += 16) {
        int i0 = adj[j], i1 = adj[j + 4], i2 = adj[j + 8], i3 = adj[j + 12];
        uint2 u0 = xsh[i0 * 4 + fv];
        uint2 u1 = xsh[i1 * 4 + fv];
        uint2 u2 = xsh[i2 * 4 + fv];
        uint2 u3 = xsh[i3 * 4 + fv];
        float4 v0 = h4_to_f4(u0), v1 = h4_to_f4(u1);
        float4 v2 = h4_to_f4(u2), v3 = h4_to_f4(u3);
        a0.x += v0.x; a0.y += v0.y; a0.z += v0.z; a0.w += v0.w;
        a1.x += v1.x; a1.y += v1.y; a1.z += v1.z; a1.w += v1.w;
        a2.x += v2.x; a2.y += v2.y; a2.z += v2.z; a2.w += v2.w;
        a3.x += v3.x; a3.y += v3.y; a3.z += v3.z; a3.w += v3.w;
    }
    for (; j < e0; j += 4) {
        float4 v = h4_to_f4(xsh[adj[j] * 4 + fv]);
        a0.x += v.x; a0.y += v.y; a0.z += v.z; a0.w += v.w;
    }
    float4 acc;
    acc.x = (a0.x + a1.x) + (a2.x + a3.x);
    acc.y = (a0.y + a1.y) + (a2.y + a3.y);
    acc.z = (a0.z + a1.z) + (a2.z + a3.z);
    acc.w = (a0.w + a1.w) + (a2.w + a3.w);
#pragma unroll
    for (int off = 4; off <= 8; off <<= 1) {
        acc.x += __shfl_xor(acc.x, off, 64);
        acc.y += __shfl_xor(acc.y, off, 64);
        acc.z += __shfl_xor(acc.z, off, 64);
        acc.w += __shfl_xor(acc.w, off, 64);
    }
    if (k == 0) {
        float4 self = h4_to_f4(xsh[n * 4 + fv]);
        float di = dinv[n];
        float4 bb = ((const float4*)b)[fv];
        float4 o;
        o.x = tanhf(di * (acc.x + self.x) + bb.x);
        o.y = tanhf(di * (acc.y + self.y) + bb.y);
        o.z = tanhf(di * (acc.z + self.z) + bb.z);
        o.w = tanhf(di * (acc.w + self.w) + bb.w);
        // layer-2 GEMM: lane fv holds h1[4fv..4fv+3]; W2 is [16][4] row-major
        const float4* W2r = (const float4*)W2;
        float4 w0 = W2r[4 * fv + 0], w1 = W2r[4 * fv + 1];
        float4 w2 = W2r[4 * fv + 2], w3 = W2r[4 * fv + 3];
        float4 p;
        p.x = o.x * w0.x + o.y * w1.x + o.z * w2.x + o.w * w3.x;
        p.y = o.x * w0.y + o.y * w1.y + o.z * w2.y + o.w * w3.y;
        p.z = o.x * w0.z + o.y * w1.z + o.z * w2.z + o.w * w3.z;
        p.w = o.x * w0.w + o.y * w1.w + o.z * w2.w + o.w * w3.w;
        p.x += __shfl_xor(p.x, 1, 64); p.x += __shfl_xor(p.x, 2, 64);
        p.y += __shfl_xor(p.y, 1, 64); p.y += __shfl_xor(p.y, 2, 64);
        p.z += __shfl_xor(p.z, 1, 64); p.z += __shfl_xor(p.z, 2, 64);
        p.w += __shfl_xor(p.w, 1, 64); p.w += __shfl_xor(p.w, 2, 64);
        float pv = (fv == 0) ? p.x : (fv == 1) ? p.y : (fv == 2) ? p.z : p.w;
        xs2[n * 4 + fv] = pv * di;
    }
}

// Pull F=4 fused with layer-3 GEMM (fp32 xs2 — L2-resident).
__global__ __launch_bounds__(256) void k_pull4g3(const float* __restrict__ xs,
                                                 const int* __restrict__ adj,
                                                 const int* __restrict__ rowstart,
                                                 const int* __restrict__ rowend,
                                                 const float* __restrict__ dinv,
                                                 const float* __restrict__ b,
                                                 const float* __restrict__ W3,
                                                 float* __restrict__ xs3) {
    const float4* xs4 = (const float4*)xs;
    int t = threadIdx.x;
    int g = t >> 3;          // node within block (32 nodes/block)
    int q = t & 7;           // edge slot 0..7
    int n = blockIdx.x * 32 + g;
    if (n >= N_NODES) return;
    int s0 = rowstart[n], e0 = rowend[n];
    float4 a0 = make_float4(0.f, 0.f, 0.f, 0.f);
    float4 a1 = a0, a2 = a0, a3 = a0;
    int j = s0 + q;
    for (; j + 24 < e0; j += 32) {
        int i0 = adj[j], i1 = adj[j + 8], i2 = adj[j + 16], i3 = adj[j + 24];
        float4 v0 = xs4[i0], v1 = xs4[i1], v2 = xs4[i2], v3 = xs4[i3];
        a0.x += v0.x; a0.y += v0.y; a0.z += v0.z; a0.w += v0.w;
        a1.x += v1.x; a1.y += v1.y; a1.z += v1.z; a1.w += v1.w;
        a2.x += v2.x; a2.y += v2.y; a2.z += v2.z; a2.w += v2.w;
        a3.x += v3.x; a3.y += v3.y; a3.z += v3.z; a3.w += v3.w;
    }
    for (; j < e0; j += 8) {
        float4 v = xs4[adj[j]];
        a0.x += v.x; a0.y += v.y; a0.z += v.z; a0.w += v.w;
    }
    float4 acc;
    acc.x = (a0.x + a1.x) + (a2.x + a3.x);
    acc.y = (a0.y + a1.y) + (a2.y + a3.y);
    acc.z = (a0.z + a1.z) + (a2.z + a3.z);
    acc.w = (a0.w + a1.w) + (a2.w + a3.w);
#pragma unroll
    for (int off = 1; off <= 4; off <<= 1) {
        acc.x += __shfl_xor(acc.x, off, 64);
        acc.y += __shfl_xor(acc.y, off, 64);
        acc.z += __shfl_xor(acc.z, off, 64);
        acc.w += __shfl_xor(acc.w, off, 64);
    }
    if (q == 0) {
        float4 self = xs4[n];
        float di = dinv[n];
        float4 o;
        o.x = tanhf(di * (acc.x + self.x) + b[0]);
        o.y = tanhf(di * (acc.y + self.y) + b[1]);
        o.z = tanhf(di * (acc.z + self.z) + b[2]);
        o.w = tanhf(di * (acc.w + self.w) + b[3]);
        float p0 = o.x * W3[0] + o.y * W3[2] + o.z * W3[4] + o.w * W3[6];
        float p1 = o.x * W3[1] + o.y * W3[3] + o.z * W3[5] + o.w * W3[7];
        ((float2*)xs3)[n] = make_float2(p0 * di, p1 * di);
    }
}

// Layer-3 pull (F=2) fused with h3 write and 2->8 classifier.
__global__ __launch_bounds__(256) void k_pull_final(const float* __restrict__ xs,
                                                    const int* __restrict__ adj,
                                                    const int* __restrict__ rowstart,
                                                    const int* __restrict__ rowend,
                                                    const float* __restrict__ dinv,
                                                    const float* __restrict__ b3,
                                                    const float* __restrict__ Wc,
                                                    const float* __restrict__ bc,
                                                    float* __restrict__ out,
                                                    float* __restrict__ h3out) {
    const float2* xs2 = (const float2*)xs;
    int t = threadIdx.x;
    int g = t >> 3;          // node within block (32 nodes/block)
    int q = t & 7;           // edge slot 0..7
    int n = blockIdx.x * 32 + g;
    if (n >= N_NODES) return;
    int s0 = rowstart[n], e0 = rowend[n];
    float2 a0 = make_float2(0.f, 0.f), a1 = a0, a2 = a0, a3 = a0;
    int j = s0 + q;
    for (; j + 24 < e0; j += 32) {
        int i0 = adj[j], i1 = adj[j + 8], i2 = adj[j + 16], i3 = adj[j + 24];
        float2 v0 = xs2[i0], v1 = xs2[i1], v2 = xs2[i2], v3 = xs2[i3];
        a0.x += v0.x; a0.y += v0.y;
        a1.x += v1.x; a1.y += v1.y;
        a2.x += v2.x; a2.y += v2.y;
        a3.x += v3.x; a3.y += v3.y;
    }
    for (; j < e0; j += 8) {
        float2 v = xs2[adj[j]];
        a0.x += v.x; a0.y += v.y;
    }
    float2 acc;
    acc.x = (a0.x + a1.x) + (a2.x + a3.x);
    acc.y = (a0.y + a1.y) + (a2.y + a3.y);
#pragma unroll
    for (int off = 1; off <= 4; off <<= 1) {
        acc.x += __shfl_xor(acc.x, off, 64);
        acc.y += __shfl_xor(acc.y, off, 64);
    }
    float va = 0.f, vb = 0.f;
    if (q == 0) {
        float2 self = xs2[n];
        float di = dinv[n];
        va = tanhf(di * (acc.x + self.x) + b3[0]);
        vb = tanhf(di * (acc.y + self.y) + b3[1]);
        ((float2*)h3out)[n] = make_float2(va, vb);
    }
    int gb = (t & 63) & ~7;
    float a0b = __shfl(va, gb, 64);
    float a1b = __shfl(vb, gb, 64);
    out[8 * n + q] = a0b * Wc[q] + a1b * Wc[8 + q] + bc[q];
}

// ---------------------------------------------------------------------------
// Atomic fallback (R4 pipeline) — only if ws is unexpectedly small
template <int F>
__global__ __launch_bounds__(256) void k_scatter(const int* __restrict__ src32,
                                                 const long long* __restrict__ src64,
                                                 const int* __restrict__ dst32,
                                                 const long long* __restrict__ dst64,
                                                 const int* __restrict__ flag,
                                                 const float* __restrict__ xs,
                                                 float* __restrict__ acc) {
    long long gid = (long long)blockIdx.x * 256 + threadIdx.x;
    int e = (int)(gid / F), f = (int)(gid % F);
    if (e < N_EDGES) {
        int is64 = *flag;
        unsigned s = load_idx(src32, src64, is64, e);
        unsigned d = load_idx(dst32, dst64, is64, e);
        if (s < N_NODES && d < N_NODES)
            atomicAdd(&acc[d * F + f], xs[s * F + f]);
    }
}
__global__ __launch_bounds__(256) void k_deg_init(float* __restrict__ deg) {
    int i = blockIdx.x * 256 + threadIdx.x;
    if (i < N_NODES) deg[i] = 1.0f;
}
__global__ __launch_bounds__(256) void k_deg_count(const int* __restrict__ dst32,
                                                   const long long* __restrict__ dst64,
                                                   const int* __restrict__ flag,
                                                   float* __restrict__ deg) {
    int e = blockIdx.x * 256 + threadIdx.x;
    if (e < N_EDGES) {
        unsigned d = load_idx(dst32, dst64, *flag, e);
        if (d < N_NODES) atomicAdd(&deg[d], 1.0f);
    }
}
__global__ __launch_bounds__(256) void k_rsqrt(float* __restrict__ deg) {
    int i = blockIdx.x * 256 + threadIdx.x;
    if (i < N_NODES) deg[i] = rsqrtf(deg[i]);
}
template <int F>
__global__ __launch_bounds__(256) void k_finish(const float* __restrict__ acc,
                                                const float* __restrict__ dinv,
                                                const float* __restrict__ b,
                                                float* __restrict__ out) {
    int i = blockIdx.x * 256 + threadIdx.x;
    if (i >= N_NODES * F) return;
    int n = i / F, f = i % F;
    out[i] = tanhf(dinv[n] * acc[i] + b[f]);
}
__global__ __launch_bounds__(256) void k_final(const float* __restrict__ acc3,
                                               const float* __restrict__ dinv,
                                               const float* __restrict__ b3,
                                               const float* __restrict__ Wc,
                                               const float* __restrict__ bc,
                                               float* __restrict__ out,
                                               float* __restrict__ h3out) {
    int n = blockIdx.x * 256 + threadIdx.x;
    if (n >= N_NODES) return;
    float di = dinv[n];
    float a0 = tanhf(di * acc3[2 * n + 0] + b3[0]);
    float a1 = tanhf(di * acc3[2 * n + 1] + b3[1]);
    h3out[2 * n + 0] = a0;
    h3out[2 * n + 1] = a1;
#pragma unroll
    for (int c = 0; c < 8; c++)
        out[8 * n + c] = a0 * Wc[c] + a1 * Wc[8 + c] + bc[c];
}
__global__ __launch_bounds__(256) void k_zero_out(float* __restrict__ out, int n) {
    int i = blockIdx.x * 256 + threadIdx.x;
    if (i < n) out[i] = 0.0f;
}

// ---------------------------------------------------------------------------
extern "C" void kernel_launch(void* const* d_in, const int* in_sizes, int n_in,
                              void* d_out, int out_size, void* d_ws, size_t ws_size,
                              hipStream_t stream) {
    float* out = (float*)d_out;
    const float* h   = (const float*)d_in[0];
    const void*  ei  = d_in[1];
    const float* W1  = (const float*)d_in[2];
    const float* b1  = (const float*)d_in[3];
    const float* W2  = (const float*)d_in[4];
    const float* b2  = (const float*)d_in[5];
    const float* W3  = (const float*)d_in[6];
    const float* b3  = (const float*)d_in[7];
    const float* Wc  = (const float*)d_in[8];
    const float* bc  = (const float*)d_in[9];

    const int*       src32 = (const int*)ei;
    const int*       dst32 = src32 + N_EDGES;
    const long long* src64 = (const long long*)ei;
    const long long* dst64 = src64 + N_EDGES;

    float* h3out = out + 8 * N_NODES;
    const int NB_E = (N_EDGES + 255) / 256;

    if (d_ws != nullptr && ws_size >= NEW_WS_BYTES) {
        // ---------------- multisplit CSR + pull path ----------------
        float* dinv    = (float*)d_ws;               // N
        int* rowstart  = (int*)(dinv + N_NODES);     // N
        int* rowend    = rowstart + N_NODES;         // N
        int* adj       = rowend + N_NODES;           // E
        int* S         = adj + N_EDGES;              // 32N == E words, shared
        __half* xsAh   = (__half*)S;                 // 16N halves (after build)
        float* xsB     = (float*)S + 16 * N_NODES;   // 16N floats
        int* P         = S;                          // E (during build)
        int* cmat      = adj;                        // NBUCK*NBLKA <= E, dead before adj written
        int* bt        = S + 3200000;                // NBUCK+1
        int* flag      = bt + NBUCK + 1;             // 1

        k_detect_i64<<<1, 64, 0, stream>>>(src32, flag);
        k_bcount<<<NBLKA, BBA, 0, stream>>>(dst32, dst64, flag, cmat);
        k_bsum<<<NBUCK, 256, 0, stream>>>(cmat, bt);
        k_btscan<<<1, 512, 0, stream>>>(bt);
        k_boffs<<<NBUCK, 256, 0, stream>>>(cmat, bt);
        k_bscatter<<<NBLKA, BBA, 0, stream>>>(src32, src64, dst32, dst64, flag, cmat, P);
        k_bbuild<<<NBUCK, 512, 0, stream>>>(P, bt, adj, rowstart, rowend, dinv);

        // layer 1: 128 -> 16, fp16 xs1 (xsAh overwrites P — P dead after k_bbuild)
        k_gemm1h<<<N_NODES / 16, 256, 0, stream>>>(h, W1, dinv, xsAh);
        // pull-1 (fp16 gather) fused with layer-2 GEMM: writes xs2 into xsB (4N fp32)
        k_pull16g2<<<(N_NODES + 15) / 16, 256, 0, stream>>>(
            xsAh, adj, rowstart, rowend, dinv, b1, W2, xsB);
        // pull-2 fused with layer-3 GEMM: writes xs3 into xsA region (2N fp32; xs1 dead)
        k_pull4g3<<<(N_NODES + 31) / 32, 256, 0, stream>>>(
            xsB, adj, rowstart, rowend, dinv, b2, W3, (float*)S);
        // pull-3 fused with classifier
        k_pull_final<<<(N_NODES + 31) / 32, 256, 0, stream>>>(
            (float*)S, adj, rowstart, rowend, dinv, b3, Wc, bc, out, h3out);
        return;
    }

    if (d_ws != nullptr && ws_size >= ATOMIC_WS_BYTES) {
        // ---------------- atomic fallback (R4) ----------------
        float* ws   = (float*)d_ws;
        float* dinv = ws;
        float* bufA = dinv + N_NODES;
        float* bufB = bufA + 16 * N_NODES;
        int*   flag = (int*)(bufB + 16 * N_NODES);
        float* xs1 = bufA, *acc1 = bufB, *h1 = bufA;
        float* xs2 = bufB, *acc2 = bufB + 4 * N_NODES, *h2 = bufA;
        float* xs3 = bufB, *acc3 = bufB + 2 * N_NODES;

        k_detect_i64<<<1, 64, 0, stream>>>(src32, flag);
        k_deg_init<<<NB_BLK, 256, 0, stream>>>(dinv);
        k_deg_count<<<NB_E, 256, 0, stream>>>(dst32, dst64, flag, dinv);
        k_rsqrt<<<NB_BLK, 256, 0, stream>>>(dinv);
        k_gemm1<<<N_NODES / 16, 256, 0, stream>>>(h, W1, dinv, xs1, acc1);
        k_scatter<16><<<(int)(((long long)N_EDGES * 16 + 255) / 256), 256, 0, stream>>>(
            src32, src64, dst32, dst64, flag, xs1, acc1);
        k_finish<16><<<(N_NODES * 16 + 255) / 256, 256, 0, stream>>>(acc1, dinv, b1, h1);
        k_gemm_small<16, 4><<<(N_NODES * 4 + 255) / 256, 256, 0, stream>>>(h1, W2, dinv, xs2, acc2);
        k_scatter<4><<<(int)(((long long)N_EDGES * 4 + 255) / 256), 256, 0, stream>>>(
            src32, src64, dst32, dst64, flag, xs2, acc2);
        k_finish<4><<<(N_NODES * 4 + 255) / 256, 256, 0, stream>>>(acc2, dinv, b2, h2);
        k_gemm_small<4, 2><<<(N_NODES * 2 + 255) / 256, 256, 0, stream>>>(h2, W3, dinv, xs3, acc3);
        k_scatter<2><<<(int)(((long long)N_EDGES * 2 + 255) / 256), 256, 0, stream>>>(
            src32, src64, dst32, dst64, flag, xs3, acc3);
        k_final<<<NB_BLK, 256, 0, stream>>>(acc3, dinv, b3, Wc, bc, out, h3out);
        return;
    }

    k_zero_out<<<(out_size + 255) / 256, 256, 0, stream>>>(out, out_size);
}

// Round 13
// 246.037 us; speedup vs baseline: 1.4589x; 1.0018x over previous
//
#include <hip/hip_runtime.h>
#include <hip/hip_fp16.h>
#include <math.h>

#define N_NODES 100000
#define N_EDGES 3200000
#define NPB    256                               // nodes per bucket
#define NBUCK  ((N_NODES + NPB - 1) / NPB)       // 391
#define NBLKA  256                               // pass-A blocks (region granularity!)
#define BBA    1024                              // pass-A block size (occupancy)
#define EPB    ((N_EDGES + NBLKA - 1) / NBLKA)   // 12500
#define NB_BLK ((N_NODES + 255) / 256)

// ws words: dinv N + rowstart N + rowend N + adj E + S max(32N,E)
//           + bt (NBUCK+1) + flag.  cmat (NBUCK*NBLKA = 100096) ALIASES adj:
//           cmat dead after k_bscatter; adj first written in k_bbuild.
#define NEW_WS_WORDS (3u*N_NODES + N_EDGES + 3200000u + NBUCK + 2u)
#define NEW_WS_BYTES (NEW_WS_WORDS * 4u)
// atomic fallback path (R4): 33N floats + flag
#define ATOMIC_WS_BYTES ((33u*N_NODES + 16u) * 4u)

// ---------------------------------------------------------------------------
// dtype probe: edge_index may be int32 or raw int64 (reference uses int64).
__global__ void k_detect_i64(const int* __restrict__ ei_words, int* __restrict__ flag) {
    if (blockIdx.x == 0 && threadIdx.x == 0) {
        int allzero = 1;
        for (int i = 0; i < 64; i++)
            if (ei_words[2 * i + 1] != 0) allzero = 0;
        *flag = allzero;  // 1 => int64 layout
    }
}

__device__ __forceinline__ unsigned load_idx(const int* p32, const long long* p64,
                                             int is64, int e) {
    return is64 ? (unsigned)(unsigned long long)p64[e] : (unsigned)p32[e];
}

// ---------------------------------------------------------------------------
// Pass A1: per-(block, bucket) edge counts, cmat[blk*NBUCK + b] (coalesced).
__global__ __launch_bounds__(BBA) void k_bcount(const int* __restrict__ dst32,
                                                const long long* __restrict__ dst64,
                                                const int* __restrict__ flag,
                                                int* __restrict__ cmat) {
    __shared__ int lc[NBUCK];
    int t = threadIdx.x, blk = blockIdx.x;
    for (int i = t; i < NBUCK; i += BBA) lc[i] = 0;
    __syncthreads();
    int is64 = *flag;
    int e0 = blk * EPB;
    int e1 = e0 + EPB; if (e1 > N_EDGES) e1 = N_EDGES;
    for (int e = e0 + t; e < e1; e += BBA) {
        unsigned d = load_idx(dst32, dst64, is64, e);
        if (d < N_NODES) atomicAdd(&lc[d >> 8], 1);
    }
    __syncthreads();
    for (int b = t; b < NBUCK; b += BBA) cmat[blk * NBUCK + b] = lc[b];
}

// Pass A2: bucket totals bt[b] = sum_blk cmat[blk][b]
__global__ __launch_bounds__(256) void k_bsum(const int* __restrict__ cmat,
                                              int* __restrict__ bt) {
    int b = blockIdx.x, t = threadIdx.x;
    int v = cmat[t * NBUCK + b];
#pragma unroll
    for (int off = 32; off > 0; off >>= 1) v += __shfl_down(v, off, 64);
    __shared__ int s[4];
    if ((t & 63) == 0) s[t >> 6] = v;
    __syncthreads();
    if (t == 0) bt[b] = s[0] + s[1] + s[2] + s[3];
}

// Pass A3: exclusive scan of bt[0..NBUCK) in one block; bt[NBUCK] = total
__global__ __launch_bounds__(512) void k_btscan(int* __restrict__ bt) {
    __shared__ int s[512];
    int t = threadIdx.x;
    s[t] = (t < NBUCK) ? bt[t] : 0;
    __syncthreads();
    for (int off = 1; off < 512; off <<= 1) {
        int v = (t >= off) ? s[t - off] : 0;
        __syncthreads();
        s[t] += v;
        __syncthreads();
    }
    if (t < NBUCK) bt[t] = (t == 0) ? 0 : s[t - 1];
    if (t == 0) bt[NBUCK] = s[NBUCK - 1];
}

// Pass A4: per-bucket column scan of cmat (over blk) + bt[b], in place
__global__ __launch_bounds__(256) void k_boffs(int* __restrict__ cmat,
                                               const int* __restrict__ bt) {
    __shared__ int s[256];
    int b = blockIdx.x, t = threadIdx.x;
    s[t] = cmat[t * NBUCK + b];
    __syncthreads();
    for (int off = 1; off < 256; off <<= 1) {
        int v = (t >= off) ? s[t - off] : 0;
        __syncthreads();
        s[t] += v;
        __syncthreads();
    }
    cmat[t * NBUCK + b] = ((t == 0) ? 0 : s[t - 1]) + bt[b];
}

// Pass A5: scatter packed entries (dstLow<<17 | src) into bucket-major P.
__global__ __launch_bounds__(BBA) void k_bscatter(const int* __restrict__ src32,
                                                  const long long* __restrict__ src64,
                                                  const int* __restrict__ dst32,
                                                  const long long* __restrict__ dst64,
                                                  const int* __restrict__ flag,
                                                  const int* __restrict__ cmat,
                                                  int* __restrict__ P) {
    __shared__ int cur[NBUCK];
    int t = threadIdx.x, blk = blockIdx.x;
    for (int i = t; i < NBUCK; i += BBA) cur[i] = cmat[blk * NBUCK + i];
    __syncthreads();
    int is64 = *flag;
    int e0 = blk * EPB;
    int e1 = e0 + EPB; if (e1 > N_EDGES) e1 = N_EDGES;
    for (int e = e0 + t; e < e1; e += BBA) {
        unsigned d = load_idx(dst32, dst64, is64, e);
        if (d < N_NODES) {
            unsigned s = load_idx(src32, src64, is64, e);
            int pos = atomicAdd(&cur[d >> 8], 1);
            P[pos] = (int)(((d & 255u) << 17) | (s & 0x1FFFFu));
        }
    }
}

// Pass B: per-bucket CSR build (one 512-thread block per 256-node bucket).
__global__ __launch_bounds__(512) void k_bbuild(const int* __restrict__ P,
                                                const int* __restrict__ bt,
                                                int* __restrict__ adj,
                                                int* __restrict__ rowstart,
                                                int* __restrict__ rowend,
                                                float* __restrict__ dinv) {
    __shared__ int cnt[NPB];
    __shared__ int s[NPB];
    int b = blockIdx.x, t = threadIdx.x;
    int bo = bt[b], be = bt[b + 1];
    if (t < NPB) cnt[t] = 0;
    __syncthreads();
    for (int i = bo + t; i < be; i += 512) atomicAdd(&cnt[P[i] >> 17], 1);
    __syncthreads();
    if (t < NPB) s[t] = cnt[t];
    __syncthreads();
    for (int off = 1; off < NPB; off <<= 1) {
        int v = (t >= off && t < NPB) ? s[t - off] : 0;
        __syncthreads();
        if (t < NPB) s[t] += v;
        __syncthreads();
    }
    int ex = (t == 0 || t >= NPB) ? 0 : s[t - 1];
    int node = b * NPB + t;
    if (t < NPB && node < N_NODES) {
        rowstart[node] = bo + ex;
        rowend[node]   = bo + ex + cnt[t];
        dinv[node]     = rsqrtf((float)cnt[t] + 1.0f);
    }
    __syncthreads();
    if (t < NPB) s[t] = ex;  // cursors
    __syncthreads();
    for (int i = bo + t; i < be; i += 512) {
        int ent = P[i];
        int pos = bo + atomicAdd(&s[ent >> 17], 1);
        adj[pos] = ent & 0x1FFFF;
    }
}

// ---------------------------------------------------------------------------
// Layer-1 GEMM (R6 anchor), fp16 output: 16 nodes/block, lane = (node, f).
__global__ __launch_bounds__(256) void k_gemm1h(const float* __restrict__ h,
                                                const float* __restrict__ W,
                                                const float* __restrict__ dinv,
                                                __half* __restrict__ xs) {
    __shared__ float Wt[16 * 132];
    __shared__ float Hs[16 * 132];
    int tid = threadIdx.x;
    for (int i = tid; i < 2048; i += 256) {
        int k = i >> 4, f = i & 15;
        Wt[f * 132 + k] = W[i];
    }
    int nodeBase = blockIdx.x * 16;
    for (int i = tid; i < 512; i += 256) {
        int r = i >> 5, c = i & 31;
        float4 v = ((const float4*)(h + (size_t)(nodeBase + r) * 128))[c];
        *((float4*)&Hs[r * 132 + c * 4]) = v;
    }
    __syncthreads();
    int nl = tid >> 4;
    int f  = tid & 15;
    int n  = nodeBase + nl;
    const float* hr = &Hs[nl * 132];
    const float* wr = &Wt[f * 132];
    float s = 0.0f;
#pragma unroll
    for (int k = 0; k < 128; k++) s += hr[k] * wr[k];
    s *= dinv[n];
    xs[n * 16 + f] = __float2half(s);
}

// fp32 variant for atomic fallback path
__global__ __launch_bounds__(256) void k_gemm1(const float* __restrict__ h,
                                               const float* __restrict__ W,
                                               const float* __restrict__ dinv,
                                               float* __restrict__ xs,
                                               float* acc) {
    __shared__ float Wt[16 * 132];
    __shared__ float Hs[16 * 132];
    int tid = threadIdx.x;
    for (int i = tid; i < 2048; i += 256) {
        int k = i >> 4, f = i & 15;
        Wt[f * 132 + k] = W[i];
    }
    int nodeBase = blockIdx.x * 16;
    for (int i = tid; i < 512; i += 256) {
        int r = i >> 5, c = i & 31;
        float4 v = ((const float4*)(h + (size_t)(nodeBase + r) * 128))[c];
        *((float4*)&Hs[r * 132 + c * 4]) = v;
    }
    __syncthreads();
    int nl = tid >> 4;
    int f  = tid & 15;
    int n  = nodeBase + nl;
    const float* hr = &Hs[nl * 132];
    const float* wr = &Wt[f * 132];
    float s = 0.0f;
#pragma unroll
    for (int k = 0; k < 128; k++) s += hr[k] * wr[k];
    s *= dinv[n];
    xs[n * 16 + f]  = s;
    acc[n * 16 + f] = s;
}

template <int FI, int FO>
__global__ __launch_bounds__(256) void k_gemm_small(const float* __restrict__ x,
                                                    const float* __restrict__ W,
                                                    const float* __restrict__ dinv,
                                                    float* __restrict__ xs,
                                                    float* acc) {
    int i = blockIdx.x * 256 + threadIdx.x;
    if (i >= N_NODES * FO) return;
    int n = i / FO, f = i % FO;
    float s = 0.0f;
#pragma unroll
    for (int k = 0; k < FI; k++) s += x[n * FI + k] * W[k * FO + f];
    s *= dinv[n];
    xs[i] = s;
    acc[i] = s;
}

// ---------------------------------------------------------------------------
// Pull F=16 (fp16 xs) fused with layer-2 GEMM. Each lane gathers 4 halves (8B).
__device__ __forceinline__ float4 h4_to_f4(uint2 u) {
    __half2 lo = *(__half2*)&u.x;
    __half2 hi = *(__half2*)&u.y;
    float2 flo = __half22float2(lo), fhi = __half22float2(hi);
    return make_float4(flo.x, flo.y, fhi.x, fhi.y);
}

__global__ __launch_bounds__(256) void k_pull16g2(const __half* __restrict__ xs,
                                                  const int* __restrict__ adj,
                                                  const int* __restrict__ rowstart,
                                                  const int* __restrict__ rowend,
                                                  const float* __restrict__ dinv,
                                                  const float* __restrict__ b,
                                                  const float* __restrict__ W2,
                                                  float* __restrict__ xs2) {
    const uint2* xsh = (const uint2*)xs;   // node row = 4 x uint2 (16 halves)
    int t = threadIdx.x;
    int g = t >> 4;          // node within block (16 nodes/block)
    int q = t & 15;
    int fv = q & 3;          // which 4-half group of the 16-half row
    int k  = q >> 2;         // edge slot 0..3
    int n = blockIdx.x * 16 + g;
    if (n >= N_NODES) return;
    int s0 = rowstart[n], e0 = rowend[n];
    float4 a0 = make_float4(0.f, 0.f, 0.f, 0.f);
    float4 a1 = a0, a2 = a0, a3 = a0;
    int j = s0 + k;
    for (; j + 12 < e0; j += 16) {
        int i0 = adj[j], i1 = adj[j + 4], i2 = adj[j + 8], i3 = adj[j + 12];
        uint2 u0 = xsh[i0 * 4 + fv];
        uint2 u1 = xsh[i1 * 4 + fv];
        uint2 u2 = xsh[i2 * 4 + fv];
        uint2 u3 = xsh[i3 * 4 + fv];
        float4 v0 = h4_to_f4(u0), v1 = h4_to_f4(u1);
        float4 v2 = h4_to_f4(u2), v3 = h4_to_f4(u3);
        a0.x += v0.x; a0.y += v0.y; a0.z += v0.z; a0.w += v0.w;
        a1.x += v1.x; a1.y += v1.y; a1.z += v1.z; a1.w += v1.w;
        a2.x += v2.x; a2.y += v2.y; a2.z += v2.z; a2.w += v2.w;
        a3.x += v3.x; a3.y += v3.y; a3.z += v3.z; a3.w += v3.w;
    }
    for (; j < e0; j += 4) {
        float4 v = h4_to_f4(xsh[adj[j] * 4 + fv]);
        a0.x += v.x; a0.y += v.y; a0.z += v.z; a0.w += v.w;
    }
    float4 acc;
    acc.x = (a0.x + a1.x) + (a2.x + a3.x);
    acc.y = (a0.y + a1.y) + (a2.y + a3.y);
    acc.z = (a0.z + a1.z) + (a2.z + a3.z);
    acc.w = (a0.w + a1.w) + (a2.w + a3.w);
#pragma unroll
    for (int off = 4; off <= 8; off <<= 1) {
        acc.x += __shfl_xor(acc.x, off, 64);
        acc.y += __shfl_xor(acc.y, off, 64);
        acc.z += __shfl_xor(acc.z, off, 64);
        acc.w += __shfl_xor(acc.w, off, 64);
    }
    if (k == 0) {
        float4 self = h4_to_f4(xsh[n * 4 + fv]);
        float di = dinv[n];
        float4 bb = ((const float4*)b)[fv];
        float4 o;
        o.x = tanhf(di * (acc.x + self.x) + bb.x);
        o.y = tanhf(di * (acc.y + self.y) + bb.y);
        o.z = tanhf(di * (acc.z + self.z) + bb.z);
        o.w = tanhf(di * (acc.w + self.w) + bb.w);
        // layer-2 GEMM: lane fv holds h1[4fv..4fv+3]; W2 is [16][4] row-major
        const float4* W2r = (const float4*)W2;
        float4 w0 = W2r[4 * fv + 0], w1 = W2r[4 * fv + 1];
        float4 w2 = W2r[4 * fv + 2], w3 = W2r[4 * fv + 3];
        float4 p;
        p.x = o.x * w0.x + o.y * w1.x + o.z * w2.x + o.w * w3.x;
        p.y = o.x * w0.y + o.y * w1.y + o.z * w2.y + o.w * w3.y;
        p.z = o.x * w0.z + o.y * w1.z + o.z * w2.z + o.w * w3.z;
        p.w = o.x * w0.w + o.y * w1.w + o.z * w2.w + o.w * w3.w;
        p.x += __shfl_xor(p.x, 1, 64); p.x += __shfl_xor(p.x, 2, 64);
        p.y += __shfl_xor(p.y, 1, 64); p.y += __shfl_xor(p.y, 2, 64);
        p.z += __shfl_xor(p.z, 1, 64); p.z += __shfl_xor(p.z, 2, 64);
        p.w += __shfl_xor(p.w, 1, 64); p.w += __shfl_xor(p.w, 2, 64);
        float pv = (fv == 0) ? p.x : (fv == 1) ? p.y : (fv == 2) ? p.z : p.w;
        xs2[n * 4 + fv] = pv * di;
    }
}

// Pull F=4 fused with layer-3 GEMM (fp32 xs2 — L2-resident).
__global__ __launch_bounds__(256) void k_pull4g3(const float* __restrict__ xs,
                                                 const int* __restrict__ adj,
                                                 const int* __restrict__ rowstart,
                                                 const int* __restrict__ rowend,
                                                 const float* __restrict__ dinv,
                                                 const float* __restrict__ b,
                                                 const float* __restrict__ W3,
                                                 float* __restrict__ xs3) {
    const float4* xs4 = (const float4*)xs;
    int t = threadIdx.x;
    int g = t >> 3;          // node within block (32 nodes/block)
    int q = t & 7;           // edge slot 0..7
    int n = blockIdx.x * 32 + g;
    if (n >= N_NODES) return;
    int s0 = rowstart[n], e0 = rowend[n];
    float4 a0 = make_float4(0.f, 0.f, 0.f, 0.f);
    float4 a1 = a0, a2 = a0, a3 = a0;
    int j = s0 + q;
    for (; j + 24 < e0; j += 32) {
        int i0 = adj[j], i1 = adj[j + 8], i2 = adj[j + 16], i3 = adj[j + 24];
        float4 v0 = xs4[i0], v1 = xs4[i1], v2 = xs4[i2], v3 = xs4[i3];
        a0.x += v0.x; a0.y += v0.y; a0.z += v0.z; a0.w += v0.w;
        a1.x += v1.x; a1.y += v1.y; a1.z += v1.z; a1.w += v1.w;
        a2.x += v2.x; a2.y += v2.y; a2.z += v2.z; a2.w += v2.w;
        a3.x += v3.x; a3.y += v3.y; a3.z += v3.z; a3.w += v3.w;
    }
    for (; j < e0; j += 8) {
        float4 v = xs4[adj[j]];
        a0.x += v.x; a0.y += v.y; a0.z += v.z; a0.w += v.w;
    }
    float4 acc;
    acc.x = (a0.x + a1.x) + (a2.x + a3.x);
    acc.y = (a0.y + a1.y) + (a2.y + a3.y);
    acc.z = (a0.z + a1.z) + (a2.z + a3.z);
    acc.w = (a0.w + a1.w) + (a2.w + a3.w);
#pragma unroll
    for (int off = 1; off <= 4; off <<= 1) {
        acc.x += __shfl_xor(acc.x, off, 64);
        acc.y += __shfl_xor(acc.y, off, 64);
        acc.z += __shfl_xor(acc.z, off, 64);
        acc.w += __shfl_xor(acc.w, off, 64);
    }
    if (q == 0) {
        float4 self = xs4[n];
        float di = dinv[n];
        float4 o;
        o.x = tanhf(di * (acc.x + self.x) + b[0]);
        o.y = tanhf(di * (acc.y + self.y) + b[1]);
        o.z = tanhf(di * (acc.z + self.z) + b[2]);
        o.w = tanhf(di * (acc.w + self.w) + b[3]);
        float p0 = o.x * W3[0] + o.y * W3[2] + o.z * W3[4] + o.w * W3[6];
        float p1 = o.x * W3[1] + o.y * W3[3] + o.z * W3[5] + o.w * W3[7];
        ((float2*)xs3)[n] = make_float2(p0 * di, p1 * di);
    }
}

// Layer-3 pull (F=2) fused with h3 write and 2->8 classifier.
__global__ __launch_bounds__(256) void k_pull_final(const float* __restrict__ xs,
                                                    const int* __restrict__ adj,
                                                    const int* __restrict__ rowstart,
                                                    const int* __restrict__ rowend,
                                                    const float* __restrict__ dinv,
                                                    const float* __restrict__ b3,
                                                    const float* __restrict__ Wc,
                                                    const float* __restrict__ bc,
                                                    float* __restrict__ out,
                                                    float* __restrict__ h3out) {
    const float2* xs2 = (const float2*)xs;
    int t = threadIdx.x;
    int g = t >> 3;          // node within block (32 nodes/block)
    int q = t & 7;           // edge slot 0..7
    int n = blockIdx.x * 32 + g;
    if (n >= N_NODES) return;
    int s0 = rowstart[n], e0 = rowend[n];
    float2 a0 = make_float2(0.f, 0.f), a1 = a0, a2 = a0, a3 = a0;
    int j = s0 + q;
    for (; j + 24 < e0; j += 32) {
        int i0 = adj[j], i1 = adj[j + 8], i2 = adj[j + 16], i3 = adj[j + 24];
        float2 v0 = xs2[i0], v1 = xs2[i1], v2 = xs2[i2], v3 = xs2[i3];
        a0.x += v0.x; a0.y += v0.y;
        a1.x += v1.x; a1.y += v1.y;
        a2.x += v2.x; a2.y += v2.y;
        a3.x += v3.x; a3.y += v3.y;
    }
    for (; j < e0; j += 8) {
        float2 v = xs2[adj[j]];
        a0.x += v.x; a0.y += v.y;
    }
    float2 acc;
    acc.x = (a0.x + a1.x) + (a2.x + a3.x);
    acc.y = (a0.y + a1.y) + (a2.y + a3.y);
#pragma unroll
    for (int off = 1; off <= 4; off <<= 1) {
        acc.x += __shfl_xor(acc.x, off, 64);
        acc.y += __shfl_xor(acc.y, off, 64);
    }
    float va = 0.f, vb = 0.f;
    if (q == 0) {
        float2 self = xs2[n];
        float di = dinv[n];
        va = tanhf(di * (acc.x + self.x) + b3[0]);
        vb = tanhf(di * (acc.y + self.y) + b3[1]);
        ((float2*)h3out)[n] = make_float2(va, vb);
    }
    int gb = (t & 63) & ~7;
    float a0b = __shfl(va, gb, 64);
    float a1b = __shfl(vb, gb, 64);
    out[8 * n + q] = a0b * Wc[q] + a1b * Wc[8 + q] + bc[q];
}

// ---------------------------------------------------------------------------
// Atomic fallback (R4 pipeline) — only if ws is unexpectedly small
template <int F>
__global__ __launch_bounds__(256) void k_scatter(const int* __restrict__ src32,
                                                 const long long* __restrict__ src64,
                                                 const int* __restrict__ dst32,
                                                 const long long* __restrict__ dst64,
                                                 const int* __restrict__ flag,
                                                 const float* __restrict__ xs,
                                                 float* __restrict__ acc) {
    long long gid = (long long)blockIdx.x * 256 + threadIdx.x;
    int e = (int)(gid / F), f = (int)(gid % F);
    if (e < N_EDGES) {
        int is64 = *flag;
        unsigned s = load_idx(src32, src64, is64, e);
        unsigned d = load_idx(dst32, dst64, is64, e);
        if (s < N_NODES && d < N_NODES)
            atomicAdd(&acc[d * F + f], xs[s * F + f]);
    }
}
__global__ __launch_bounds__(256) void k_deg_init(float* __restrict__ deg) {
    int i = blockIdx.x * 256 + threadIdx.x;
    if (i < N_NODES) deg[i] = 1.0f;
}
__global__ __launch_bounds__(256) void k_deg_count(const int* __restrict__ dst32,
                                                   const long long* __restrict__ dst64,
                                                   const int* __restrict__ flag,
                                                   float* __restrict__ deg) {
    int e = blockIdx.x * 256 + threadIdx.x;
    if (e < N_EDGES) {
        unsigned d = load_idx(dst32, dst64, *flag, e);
        if (d < N_NODES) atomicAdd(&deg[d], 1.0f);
    }
}
__global__ __launch_bounds__(256) void k_rsqrt(float* __restrict__ deg) {
    int i = blockIdx.x * 256 + threadIdx.x;
    if (i < N_NODES) deg[i] = rsqrtf(deg[i]);
}
template <int F>
__global__ __launch_bounds__(256) void k_finish(const float* __restrict__ acc,
                                                const float* __restrict__ dinv,
                                                const float* __restrict__ b,
                                                float* __restrict__ out) {
    int i = blockIdx.x * 256 + threadIdx.x;
    if (i >= N_NODES * F) return;
    int n = i / F, f = i % F;
    out[i] = tanhf(dinv[n] * acc[i] + b[f]);
}
__global__ __launch_bounds__(256) void k_final(const float* __restrict__ acc3,
                                               const float* __restrict__ dinv,
                                               const float* __restrict__ b3,
                                               const float* __restrict__ Wc,
                                               const float* __restrict__ bc,
                                               float* __restrict__ out,
                                               float* __restrict__ h3out) {
    int n = blockIdx.x * 256 + threadIdx.x;
    if (n >= N_NODES) return;
    float di = dinv[n];
    float a0 = tanhf(di * acc3[2 * n + 0] + b3[0]);
    float a1 = tanhf(di * acc3[2 * n + 1] + b3[1]);
    h3out[2 * n + 0] = a0;
    h3out[2 * n + 1] = a1;
#pragma unroll
    for (int c = 0; c < 8; c++)
        out[8 * n + c] = a0 * Wc[c] + a1 * Wc[8 + c] + bc[c];
}
__global__ __launch_bounds__(256) void k_zero_out(float* __restrict__ out, int n) {
    int i = blockIdx.x * 256 + threadIdx.x;
    if (i < n) out[i] = 0.0f;
}

// ---------------------------------------------------------------------------
extern "C" void kernel_launch(void* const* d_in, const int* in_sizes, int n_in,
                              void* d_out, int out_size, void* d_ws, size_t ws_size,
                              hipStream_t stream) {
    float* out = (float*)d_out;
    const float* h   = (const float*)d_in[0];
    const void*  ei  = d_in[1];
    const float* W1  = (const float*)d_in[2];
    const float* b1  = (const float*)d_in[3];
    const float* W2  = (const float*)d_in[4];
    const float* b2  = (const float*)d_in[5];
    const float* W3  = (const float*)d_in[6];
    const float* b3  = (const float*)d_in[7];
    const float* Wc  = (const float*)d_in[8];
    const float* bc  = (const float*)d_in[9];

    const int*       src32 = (const int*)ei;
    const int*       dst32 = src32 + N_EDGES;
    const long long* src64 = (const long long*)ei;
    const long long* dst64 = src64 + N_EDGES;

    float* h3out = out + 8 * N_NODES;
    const int NB_E = (N_EDGES + 255) / 256;

    if (d_ws != nullptr && ws_size >= NEW_WS_BYTES) {
        // ---------------- multisplit CSR + pull path ----------------
        float* dinv    = (float*)d_ws;               // N
        int* rowstart  = (int*)(dinv + N_NODES);     // N
        int* rowend    = rowstart + N_NODES;         // N
        int* adj       = rowend + N_NODES;           // E
        int* S         = adj + N_EDGES;              // 32N == E words, shared
        __half* xsAh   = (__half*)S;                 // 16N halves (after build)
        float* xsB     = (float*)S + 16 * N_NODES;   // 16N floats
        int* P         = S;                          // E (during build)
        int* cmat      = adj;                        // NBUCK*NBLKA <= E, dead before adj written
        int* bt        = S + 3200000;                // NBUCK+1
        int* flag      = bt + NBUCK + 1;             // 1

        k_detect_i64<<<1, 64, 0, stream>>>(src32, flag);
        k_bcount<<<NBLKA, BBA, 0, stream>>>(dst32, dst64, flag, cmat);
        k_bsum<<<NBUCK, 256, 0, stream>>>(cmat, bt);
        k_btscan<<<1, 512, 0, stream>>>(bt);
        k_boffs<<<NBUCK, 256, 0, stream>>>(cmat, bt);
        k_bscatter<<<NBLKA, BBA, 0, stream>>>(src32, src64, dst32, dst64, flag, cmat, P);
        k_bbuild<<<NBUCK, 512, 0, stream>>>(P, bt, adj, rowstart, rowend, dinv);

        // layer 1: 128 -> 16, fp16 xs1 (xsAh overwrites P — P dead after k_bbuild)
        k_gemm1h<<<N_NODES / 16, 256, 0, stream>>>(h, W1, dinv, xsAh);
        // pull-1 (fp16 uint2 gather) fused with layer-2 GEMM: writes xs2 into xsB
        k_pull16g2<<<(N_NODES + 15) / 16, 256, 0, stream>>>(
            xsAh, adj, rowstart, rowend, dinv, b1, W2, xsB);
        // pull-2 fused with layer-3 GEMM: writes xs3 into xsA region (xs1 dead)
        k_pull4g3<<<(N_NODES + 31) / 32, 256, 0, stream>>>(
            xsB, adj, rowstart, rowend, dinv, b2, W3, (float*)S);
        // pull-3 fused with classifier
        k_pull_final<<<(N_NODES + 31) / 32, 256, 0, stream>>>(
            (float*)S, adj, rowstart, rowend, dinv, b3, Wc, bc, out, h3out);
        return;
    }

    if (d_ws != nullptr && ws_size >= ATOMIC_WS_BYTES) {
        // ---------------- atomic fallback (R4) ----------------
        float* ws   = (float*)d_ws;
        float* dinv = ws;
        float* bufA = dinv + N_NODES;
        float* bufB = bufA + 16 * N_NODES;
        int*   flag = (int*)(bufB + 16 * N_NODES);
        float* xs1 = bufA, *acc1 = bufB, *h1 = bufA;
        float* xs2 = bufB, *acc2 = bufB + 4 * N_NODES, *h2 = bufA;
        float* xs3 = bufB, *acc3 = bufB + 2 * N_NODES;

        k_detect_i64<<<1, 64, 0, stream>>>(src32, flag);
        k_deg_init<<<NB_BLK, 256, 0, stream>>>(dinv);
        k_deg_count<<<NB_E, 256, 0, stream>>>(dst32, dst64, flag, dinv);
        k_rsqrt<<<NB_BLK, 256, 0, stream>>>(dinv);
        k_gemm1<<<N_NODES / 16, 256, 0, stream>>>(h, W1, dinv, xs1, acc1);
        k_scatter<16><<<(int)(((long long)N_EDGES * 16 + 255) / 256), 256, 0, stream>>>(
            src32, src64, dst32, dst64, flag, xs1, acc1);
        k_finish<16><<<(N_NODES * 16 + 255) / 256, 256, 0, stream>>>(acc1, dinv, b1, h1);
        k_gemm_small<16, 4><<<(N_NODES * 4 + 255) / 256, 256, 0, stream>>>(h1, W2, dinv, xs2, acc2);
        k_scatter<4><<<(int)(((long long)N_EDGES * 4 + 255) / 256), 256, 0, stream>>>(
            src32, src64, dst32, dst64, flag, xs2, acc2);
        k_finish<4><<<(N_NODES * 4 + 255) / 256, 256, 0, stream>>>(acc2, dinv, b2, h2);
        k_gemm_small<4, 2><<<(N_NODES * 2 + 255) / 256, 256, 0, stream>>>(h2, W3, dinv, xs3, acc3);
        k_scatter<2><<<(int)(((long long)N_EDGES * 2 + 255) / 256), 256, 0, stream>>>(
            src32, src64, dst32, dst64, flag, xs3, acc3);
        k_final<<<NB_BLK, 256, 0, stream>>>(acc3, dinv, b3, Wc, bc, out, h3out);
        return;
    }

    k_zero_out<<<(out_size + 255) / 256, 256, 0, stream>>>(out, out_size);
}